// Round 6
// baseline (796.761 us; speedup 1.0000x reference)
//
#include <hip/hip_runtime.h>
#include <hip/hip_bf16.h>
#include <math.h>

#define N_RESC 10000
#define N_EDGEC 320000
#define C_SC 384
#define C_ZC 128
#define AGG_D 864
#define FEAT_D 960
#define OUT_D 384

// scales
#define S1C 0.14433756729740643f   /* sqrt(1/48) */
#define S2C 0.5773502691896258f    /* sqrt(1/3)  */
#define SHWC 0.13608276348795434f  /* sqrt(1/54) */

__global__ void k_zero(int* cursor) {
    int i = blockIdx.x * 256 + threadIdx.x;
    if (i < N_RESC) cursor[i] = 0;
}

__global__ void k_hist(const int* __restrict__ ei, int* cursor) {
    int e = blockIdx.x * 256 + threadIdx.x;
    if (e < N_EDGEC) atomicAdd(&cursor[ei[N_EDGEC + e]], 1);
}

__global__ __launch_bounds__(1024) void k_scan(int* cursor, int* rowptr) {
    __shared__ int buf[1024];
    __shared__ int carry_s;
    int t = threadIdx.x;
    if (t == 0) carry_s = 0;
    __syncthreads();
    for (int ch = 0; ch < 10; ++ch) {
        int idx = ch * 1024 + t;
        int v = (idx < N_RESC) ? cursor[idx] : 0;
        buf[t] = v;
        __syncthreads();
        for (int off = 1; off < 1024; off <<= 1) {
            int x = (t >= off) ? buf[t - off] : 0;
            __syncthreads();
            buf[t] += x;
            __syncthreads();
        }
        int incl = buf[t];
        int excl = incl - v;
        int base = carry_s;
        int total = buf[1023];
        if (idx < N_RESC) { rowptr[idx] = base + excl; cursor[idx] = base + excl; }
        __syncthreads();
        if (t == 0) carry_s = base + total;
        __syncthreads();
    }
    if (t == 0) rowptr[N_RESC] = carry_s;
}

// also records inverse permutation epos[e] = CSR position
__global__ void k_scatter(const int* __restrict__ ei, int* cursor, int* csr,
                          int* src_csr, int* epos) {
    int e = blockIdx.x * 256 + threadIdx.x;
    if (e < N_EDGEC) {
        int d = ei[N_EDGEC + e];
        int s = ei[e];
        int pos = atomicAdd(&cursor[d], 1);
        csr[pos] = e;
        src_csr[pos] = s;
        epos[e] = pos;
    }
}

// ---- repack projection weights [384][1152] + z-proj weights [128][48] ----
// wpack col map: [0,192)=wq | [192,576)=wkv | [576,720)=wqp | [720,1152)=wkvp
// wzpack col map: [0,12)=wb | [12,44)=wdz | [44,48)=zero pad
__global__ __launch_bounds__(256) void k_wpack(
    const float* __restrict__ wq, const float* __restrict__ bq,
    const float* __restrict__ wkv, const float* __restrict__ bkv,
    const float* __restrict__ wqp, const float* __restrict__ bqp,
    const float* __restrict__ wkvp, const float* __restrict__ bkvp,
    const float* __restrict__ wb, const float* __restrict__ bb,
    const float* __restrict__ wdz, const float* __restrict__ bdz,
    float* __restrict__ wpack, float* __restrict__ bpack,
    float* __restrict__ wzpack, float* __restrict__ bzpack) {
    int idx = blockIdx.x * 256 + threadIdx.x;
    if (idx < 384 * 1152) {
        int j = idx / 1152, c = idx % 1152;
        float v;
        if (c < 192)      v = wq[j * 192 + c];
        else if (c < 576) v = wkv[j * 384 + (c - 192)];
        else if (c < 720) v = wqp[j * 144 + (c - 576)];
        else              v = wkvp[j * 432 + (c - 720)];
        wpack[idx] = v;
    }
    if (idx < 1152) {
        float b;
        if (idx < 192)      b = bq[idx];
        else if (idx < 576) b = bkv[idx - 192];
        else if (idx < 720) b = bqp[idx - 576];
        else                b = bkvp[idx - 720];
        bpack[idx] = b;
    }
    if (idx < 128 * 48) {
        int j = idx / 48, c = idx % 48;
        float v = 0.f;
        if (c < 12)      v = wb[j * 12 + c];
        else if (c < 44) v = wdz[j * 32 + (c - 12)];
        wzpack[idx] = v;
    }
    if (idx < 48) {
        float b = 0.f;
        if (idx < 12)      b = bb[idx];
        else if (idx < 44) b = bdz[idx - 12];
        bzpack[idx] = b;
    }
}

// ---- node projections: tiled fp32 GEMM  [10000 x 384] @ [384 x 1152] ----
// T14 async-STAGE: prologue loads chunk0 to regs; per iter:
// {reg->LDS; barrier; issue next chunk loads; compute; barrier}.
// vmcnt wait lands at next iter's LDS write, hidden under 32x32 FMA.
#define BM 64
#define BN 128
#define BK 32
__global__ __launch_bounds__(256) void k_proj(const float* __restrict__ s,
    const float* __restrict__ wpack, const float* __restrict__ bpack,
    float* __restrict__ qh, float* __restrict__ kh, float* __restrict__ vh,
    float* __restrict__ praw) {
    __shared__ float sT[BK][BM + 4];
    __shared__ float wt[BK][BN];
    int t = threadIdx.x;
    int bm0 = blockIdx.x * BM;
    int bn0 = blockIdx.y * BN;
    int tcol = t & 31;
    int trow = t >> 5;
    int c0 = tcol * 4;
    int r0 = trow * 8;

    int srow = t >> 2;
    int skoff = (t & 3) * 8;
    int gsrow = min(bm0 + srow, N_RESC - 1);
    const float* srcp = s + (long)gsrow * C_SC + skoff;
    int wrow = t >> 5;   // + q*8
    const float* wp = wpack + (long)wrow * 1152 + bn0 + c0;

    float acc[8][4];
    #pragma unroll
    for (int i = 0; i < 8; i++)
        #pragma unroll
        for (int j = 0; j < 4; j++) acc[i][j] = 0.f;

    // prologue: chunk 0 -> regs
    float4 sa = *(const float4*)(srcp + 0);
    float4 sb = *(const float4*)(srcp + 4);
    float4 wv0 = *(const float4*)(wp + 0 * 8 * 1152);
    float4 wv1 = *(const float4*)(wp + 1 * 8 * 1152);
    float4 wv2 = *(const float4*)(wp + 2 * 8 * 1152);
    float4 wv3 = *(const float4*)(wp + 3 * 8 * 1152);

    for (int k0 = 0; k0 < C_SC; k0 += BK) {
        // write staged regs -> LDS (prev compute finished at loop-end barrier)
        sT[skoff + 0][srow] = sa.x; sT[skoff + 1][srow] = sa.y;
        sT[skoff + 2][srow] = sa.z; sT[skoff + 3][srow] = sa.w;
        sT[skoff + 4][srow] = sb.x; sT[skoff + 5][srow] = sb.y;
        sT[skoff + 6][srow] = sb.z; sT[skoff + 7][srow] = sb.w;
        *(float4*)&wt[wrow + 0 * 8][c0] = wv0;
        *(float4*)&wt[wrow + 1 * 8][c0] = wv1;
        *(float4*)&wt[wrow + 2 * 8][c0] = wv2;
        *(float4*)&wt[wrow + 3 * 8][c0] = wv3;
        __syncthreads();
        // issue next chunk's loads (latency hides under compute below)
        if (k0 + BK < C_SC) {
            sa = *(const float4*)(srcp + k0 + BK);
            sb = *(const float4*)(srcp + k0 + BK + 4);
            const float* wpn = wp + (long)(k0 + BK) * 1152;
            wv0 = *(const float4*)(wpn + 0 * 8 * 1152);
            wv1 = *(const float4*)(wpn + 1 * 8 * 1152);
            wv2 = *(const float4*)(wpn + 2 * 8 * 1152);
            wv3 = *(const float4*)(wpn + 3 * 8 * 1152);
        }
        #pragma unroll
        for (int k = 0; k < BK; k++) {
            float4 a0 = *(const float4*)&sT[k][r0];
            float4 a1 = *(const float4*)&sT[k][r0 + 4];
            float4 b  = *(const float4*)&wt[k][c0];
            float av0 = a0.x, av1 = a0.y, av2 = a0.z, av3 = a0.w;
            float av4 = a1.x, av5 = a1.y, av6 = a1.z, av7 = a1.w;
            acc[0][0] = fmaf(av0, b.x, acc[0][0]); acc[0][1] = fmaf(av0, b.y, acc[0][1]);
            acc[0][2] = fmaf(av0, b.z, acc[0][2]); acc[0][3] = fmaf(av0, b.w, acc[0][3]);
            acc[1][0] = fmaf(av1, b.x, acc[1][0]); acc[1][1] = fmaf(av1, b.y, acc[1][1]);
            acc[1][2] = fmaf(av1, b.z, acc[1][2]); acc[1][3] = fmaf(av1, b.w, acc[1][3]);
            acc[2][0] = fmaf(av2, b.x, acc[2][0]); acc[2][1] = fmaf(av2, b.y, acc[2][1]);
            acc[2][2] = fmaf(av2, b.z, acc[2][2]); acc[2][3] = fmaf(av2, b.w, acc[2][3]);
            acc[3][0] = fmaf(av3, b.x, acc[3][0]); acc[3][1] = fmaf(av3, b.y, acc[3][1]);
            acc[3][2] = fmaf(av3, b.z, acc[3][2]); acc[3][3] = fmaf(av3, b.w, acc[3][3]);
            acc[4][0] = fmaf(av4, b.x, acc[4][0]); acc[4][1] = fmaf(av4, b.y, acc[4][1]);
            acc[4][2] = fmaf(av4, b.z, acc[4][2]); acc[4][3] = fmaf(av4, b.w, acc[4][3]);
            acc[5][0] = fmaf(av5, b.x, acc[5][0]); acc[5][1] = fmaf(av5, b.y, acc[5][1]);
            acc[5][2] = fmaf(av5, b.z, acc[5][2]); acc[5][3] = fmaf(av5, b.w, acc[5][3]);
            acc[6][0] = fmaf(av6, b.x, acc[6][0]); acc[6][1] = fmaf(av6, b.y, acc[6][1]);
            acc[6][2] = fmaf(av6, b.z, acc[6][2]); acc[6][3] = fmaf(av6, b.w, acc[6][3]);
            acc[7][0] = fmaf(av7, b.x, acc[7][0]); acc[7][1] = fmaf(av7, b.y, acc[7][1]);
            acc[7][2] = fmaf(av7, b.z, acc[7][2]); acc[7][3] = fmaf(av7, b.w, acc[7][3]);
        }
        __syncthreads();
    }
    #pragma unroll
    for (int j = 0; j < 4; j++) {
        int c = bn0 + c0 + j;
        float bv = bpack[c];
        #pragma unroll
        for (int i = 0; i < 8; i++) {
            int n = bm0 + r0 + i;
            if (n < N_RESC) {
                float val = acc[i][j] + bv;
                if (c < 192) qh[(long)n * 192 + c] = val;
                else if (c < 576) {
                    int cc = c - 192; int h = cc >> 5, r = cc & 31;
                    if (r < 16) kh[(long)n * 192 + h * 16 + r] = val;
                    else        vh[(long)n * 192 + h * 16 + (r - 16)] = val;
                } else praw[(long)n * 576 + (c - 576)] = val;
            }
        }
    }
}

// ---- rotate/translate raw point projections into global frame, split layouts ----
__global__ __launch_bounds__(192) void k_rot(const float* __restrict__ praw,
    const float* __restrict__ rot, const float* __restrict__ trans,
    float* __restrict__ qpts, float* __restrict__ kpts, float* __restrict__ vpts) {
    int n = blockIdx.x;
    int t = threadIdx.x;
    __shared__ float R[9], T[3];
    if (t < 9) R[t] = rot[n * 9 + t];
    if (t < 3) T[t] = trans[n * 3 + t];
    __syncthreads();
    const float* pr = praw + (long)n * 576;
    if (t < 48) {
        float x0 = pr[t], x1 = pr[48 + t], x2 = pr[96 + t];
        #pragma unroll
        for (int i = 0; i < 3; i++)
            qpts[(long)n * 144 + t * 3 + i] = R[i*3+0]*x0 + R[i*3+1]*x1 + R[i*3+2]*x2 + T[i];
    } else {
        int p = t - 48;
        float x0 = pr[144 + p], x1 = pr[288 + p], x2 = pr[432 + p];
        int h = p / 12, pp = p % 12;
        #pragma unroll
        for (int i = 0; i < 3; i++) {
            float val = R[i*3+0]*x0 + R[i*3+1]*x1 + R[i*3+2]*x2 + T[i];
            if (pp < 4) kpts[(long)n * 144 + (h * 4 + pp) * 3 + i] = val;
            else        vpts[(long)n * 288 + (h * 8 + (pp - 4)) * 3 + i] = val;
        }
    }
}

// ---- edge GEMM as tiled GEMM: [320000 x 128] @ [128 x 48(44)] ----
// async-STAGE version: z chunk prefetched into regs during compute.
#define ZBM 128
__global__ __launch_bounds__(256) void k_zproj(const float* __restrict__ z,
    const int* __restrict__ epos,
    const float* __restrict__ wzpack, const float* __restrict__ bzpack,
    float* __restrict__ b_e, float* __restrict__ pairz) {
    __shared__ float zT[32][ZBM + 4];
    __shared__ float wl[128][48];
    int t = threadIdx.x;
    long e0 = (long)blockIdx.x * ZBM;
    int er = t & 31;        // 4 edges: er*4 .. +3
    int cg = t >> 5;        // 6 cols:  cg*6 .. +5
    int cb = cg * 6;

    #pragma unroll
    for (int q = 0; q < 6; q++) {
        int f = t + q * 256;
        int row = f / 12, c4 = f % 12;
        *(float4*)&wl[row][c4 * 4] = *(const float4*)(wzpack + row * 48 + c4 * 4);
    }

    float acc[4][6];
    #pragma unroll
    for (int i = 0; i < 4; i++)
        #pragma unroll
        for (int j = 0; j < 6; j++) acc[i][j] = 0.f;

    int r = t >> 1, ch2 = t & 1;
    const float* zp = z + (e0 + r) * C_ZC + ch2 * 16;
    int kk0 = ch2 * 16;

    // prologue: chunk 0
    float4 pz0 = *(const float4*)(zp + 0);
    float4 pz1 = *(const float4*)(zp + 4);
    float4 pz2 = *(const float4*)(zp + 8);
    float4 pz3 = *(const float4*)(zp + 12);

    for (int kc = 0; kc < 4; kc++) {
        if (kc) __syncthreads();   // all waves done reading previous zT
        zT[kk0 + 0][r] = pz0.x;  zT[kk0 + 1][r] = pz0.y;
        zT[kk0 + 2][r] = pz0.z;  zT[kk0 + 3][r] = pz0.w;
        zT[kk0 + 4][r] = pz1.x;  zT[kk0 + 5][r] = pz1.y;
        zT[kk0 + 6][r] = pz1.z;  zT[kk0 + 7][r] = pz1.w;
        zT[kk0 + 8][r] = pz2.x;  zT[kk0 + 9][r] = pz2.y;
        zT[kk0 + 10][r] = pz2.z; zT[kk0 + 11][r] = pz2.w;
        zT[kk0 + 12][r] = pz3.x; zT[kk0 + 13][r] = pz3.y;
        zT[kk0 + 14][r] = pz3.z; zT[kk0 + 15][r] = pz3.w;
        __syncthreads();
        if (kc < 3) {
            const float* zpn = zp + (kc + 1) * 32;
            pz0 = *(const float4*)(zpn + 0);
            pz1 = *(const float4*)(zpn + 4);
            pz2 = *(const float4*)(zpn + 8);
            pz3 = *(const float4*)(zpn + 12);
        }
        #pragma unroll
        for (int k = 0; k < 32; k++) {
            float4 zv = *(const float4*)&zT[k][er * 4];
            const float* wrow = &wl[kc * 32 + k][cb];
            float w0 = wrow[0], w1 = wrow[1], w2 = wrow[2];
            float w3 = wrow[3], w4 = wrow[4], w5 = wrow[5];
            acc[0][0] = fmaf(zv.x, w0, acc[0][0]); acc[0][1] = fmaf(zv.x, w1, acc[0][1]);
            acc[0][2] = fmaf(zv.x, w2, acc[0][2]); acc[0][3] = fmaf(zv.x, w3, acc[0][3]);
            acc[0][4] = fmaf(zv.x, w4, acc[0][4]); acc[0][5] = fmaf(zv.x, w5, acc[0][5]);
            acc[1][0] = fmaf(zv.y, w0, acc[1][0]); acc[1][1] = fmaf(zv.y, w1, acc[1][1]);
            acc[1][2] = fmaf(zv.y, w2, acc[1][2]); acc[1][3] = fmaf(zv.y, w3, acc[1][3]);
            acc[1][4] = fmaf(zv.y, w4, acc[1][4]); acc[1][5] = fmaf(zv.y, w5, acc[1][5]);
            acc[2][0] = fmaf(zv.z, w0, acc[2][0]); acc[2][1] = fmaf(zv.z, w1, acc[2][1]);
            acc[2][2] = fmaf(zv.z, w2, acc[2][2]); acc[2][3] = fmaf(zv.z, w3, acc[2][3]);
            acc[2][4] = fmaf(zv.z, w4, acc[2][4]); acc[2][5] = fmaf(zv.z, w5, acc[2][5]);
            acc[3][0] = fmaf(zv.w, w0, acc[3][0]); acc[3][1] = fmaf(zv.w, w1, acc[3][1]);
            acc[3][2] = fmaf(zv.w, w2, acc[3][2]); acc[3][3] = fmaf(zv.w, w3, acc[3][3]);
            acc[3][4] = fmaf(zv.w, w4, acc[3][4]); acc[3][5] = fmaf(zv.w, w5, acc[3][5]);
        }
    }

    float bz0 = bzpack[cb + 0], bz1 = bzpack[cb + 1], bz2 = bzpack[cb + 2];
    float bz3 = bzpack[cb + 3], bz4 = bzpack[cb + 4], bz5 = bzpack[cb + 5];
    #pragma unroll
    for (int ei = 0; ei < 4; ei++) {
        long pos = epos[e0 + er * 4 + ei];
        float o0 = acc[ei][0] + bz0, o1 = acc[ei][1] + bz1;
        float o2 = acc[ei][2] + bz2, o3 = acc[ei][3] + bz3;
        float o4 = acc[ei][4] + bz4, o5 = acc[ei][5] + bz5;
        if (cb < 12) {
            float* d = b_e + pos * 12 + cb;
            *(float2*)(d + 0) = make_float2(o0, o1);
            *(float2*)(d + 2) = make_float2(o2, o3);
            *(float2*)(d + 4) = make_float2(o4, o5);
        } else if (cb < 42) {
            float* d = pairz + pos * 32 + (cb - 12);
            *(float2*)(d + 0) = make_float2(o0, o1);
            *(float2*)(d + 2) = make_float2(o2, o3);
            *(float2*)(d + 4) = make_float2(o4, o5);
        } else {
            *(float2*)(pairz + pos * 32 + 30) = make_float2(o0, o1);
        }
    }
}

// ---- logits in CSR (dst) order: q staged per node, 2 edges/wave-iter for MLP ----
#define CAPL 256
__global__ __launch_bounds__(256) void k_logit(const int* __restrict__ rowptr,
    const int* __restrict__ src_csr,
    const float* __restrict__ qh, const float* __restrict__ kh,
    const float* __restrict__ qpts, const float* __restrict__ kpts,
    const float* __restrict__ mask, const float* __restrict__ head_w,
    const float* __restrict__ b_e, float* __restrict__ alog) {
    int n = blockIdx.x;
    int t = threadIdx.x;
    __shared__ float qf[192], qp[144], hws[12];
    __shared__ int slist[CAPL];
    if (t < 192) qf[t] = qh[(long)n * 192 + t];
    if (t < 144) qp[t] = qpts[(long)n * 144 + t];
    if (t < 12)  hws[t] = log1pf(expf(head_w[t])) * SHWC;
    float mdst = mask[n];
    int row0 = rowptr[n];
    int deg = rowptr[n + 1] - row0;
    int w = t >> 6, l = t & 63, c = l & 15, hq = l >> 4;
    for (int cs = 0; cs < deg; cs += CAPL) {
        int cnt = min(CAPL, deg - cs);
        __syncthreads();
        for (int i = t; i < cnt; i += 256) slist[i] = src_csr[row0 + cs + i];
        __syncthreads();
        for (int i = w * 2; i < cnt; i += 8) {
            int i1 = min(i + 1, cnt - 1);
            int s0 = slist[i], s1 = slist[i1];
            int pos0 = row0 + cs + i, pos1 = row0 + cs + i1;
            float em0 = 100000.0f * (mask[s0] * mdst - 1.0f);
            float em1 = 100000.0f * (mask[s1] * mdst - 1.0f);
            float kv0[3], kv1[3];
            #pragma unroll
            for (int tp = 0; tp < 3; tp++) {
                kv0[tp] = kh[(long)s0 * 192 + tp * 64 + l];
                kv1[tp] = kh[(long)s1 * 192 + tp * 64 + l];
            }
            float kp0[3] = {0.f,0.f,0.f}, kp1[3] = {0.f,0.f,0.f};
            if (c < 12) {
                #pragma unroll
                for (int tp = 0; tp < 3; tp++) {
                    int h = tp * 4 + hq;
                    kp0[tp] = kpts[(long)s0 * 144 + h * 12 + c];
                    kp1[tp] = kpts[(long)s1 * 144 + h * 12 + c];
                }
            }
            float be0[3] = {0.f,0.f,0.f}, be1[3] = {0.f,0.f,0.f};
            if (c == 0) {
                #pragma unroll
                for (int tp = 0; tp < 3; tp++) {
                    int h = tp * 4 + hq;
                    be0[tp] = b_e[(long)pos0 * 12 + h];
                    be1[tp] = b_e[(long)pos1 * 12 + h];
                }
            }
            #pragma unroll
            for (int tp = 0; tp < 3; tp++) {
                int h = tp * 4 + hq;
                float qfv = S1C * qf[h * 16 + c];
                float val0 = qfv * kv0[tp];
                float val1 = qfv * kv1[tp];
                if (c < 12) {
                    float qpv = qp[h * 12 + c];
                    float hw = -0.5f * hws[h];
                    float d0 = qpv - kp0[tp];
                    float d1 = qpv - kp1[tp];
                    val0 = fmaf(hw * d0, d0, val0);
                    val1 = fmaf(hw * d1, d1, val1);
                }
                val0 += __shfl_xor(val0, 8, 16); val1 += __shfl_xor(val1, 8, 16);
                val0 += __shfl_xor(val0, 4, 16); val1 += __shfl_xor(val1, 4, 16);
                val0 += __shfl_xor(val0, 2, 16); val1 += __shfl_xor(val1, 2, 16);
                val0 += __shfl_xor(val0, 1, 16); val1 += __shfl_xor(val1, 1, 16);
                if (c == 0) {
                    alog[(long)pos0 * 12 + h] = val0 + S2C * be0[tp] + em0;
                    if (i1 != i)
                        alog[(long)pos1 * 12 + h] = val1 + S2C * be1[tp] + em1;
                }
            }
        }
    }
}

// ---- per-node segment softmax + weighted aggregation, float4 per thread ----
#define CAPE 256
__global__ __launch_bounds__(256) void k_agg(const int* __restrict__ rowptr,
    const int* __restrict__ src_csr,
    const float* __restrict__ alog, const float* __restrict__ vh,
    const float* __restrict__ vpts, const float* __restrict__ pairz,
    float* __restrict__ agg) {
    int n = blockIdx.x;
    int t = threadIdx.x;
    __shared__ float red[16 * 12];
    __shared__ float mh[12], linv[12];
    __shared__ float al[CAPE * 12];
    __shared__ int sl_[CAPE];
    int row0 = rowptr[n];
    int deg = rowptr[n + 1] - row0;
    int g = t >> 4, l16 = t & 15;
    if (l16 < 12) {
        float lm = -1e30f;
        for (int i = g; i < deg; i += 16)
            lm = fmaxf(lm, alog[(long)(row0 + i) * 12 + l16]);
        red[g * 12 + l16] = lm;
    }
    __syncthreads();
    if (t < 12) {
        float m = -1e30f;
        for (int gg = 0; gg < 16; gg++) m = fmaxf(m, red[gg * 12 + t]);
        mh[t] = m;
    }
    __syncthreads();
    if (l16 < 12) {
        float m = mh[l16];
        float ls = 0.f;
        for (int i = g; i < deg; i += 16)
            ls += expf(alog[(long)(row0 + i) * 12 + l16] - m);
        red[g * 12 + l16] = ls;
    }
    __syncthreads();
    if (t < 12) {
        float ssum = 0.f;
        for (int gg = 0; gg < 16; gg++) ssum += red[gg * 12 + t];
        linv[t] = 1.f / (ssum + 1e-16f);
    }

    const float* base = nullptr;
    int scale = 0, hk = 0, use_e = 0;
    int comp = t * 4;
    if (comp < 192)      { base = vh + comp; scale = 192; hk = comp >> 4; }
    else if (comp < 480) { int idx = comp - 192; base = vpts + idx; scale = 288; hk = idx / 24; }
    else if (comp < 864) { int idx = comp - 480; base = pairz + (idx & 31); scale = 32; hk = idx >> 5; use_e = 1; }
    float4 acc = make_float4(0.f, 0.f, 0.f, 0.f);

    for (int cs = 0; cs < deg; cs += CAPE) {
        int cnt = min(CAPE, deg - cs);
        int p0 = row0 + cs;
        __syncthreads();
        for (int i = t; i < cnt * 12; i += 256) {
            int h = i % 12;
            al[i] = expf(alog[(long)p0 * 12 + i] - mh[h]) * linv[h];
        }
        for (int i = t; i < cnt; i += 256) sl_[i] = src_csr[p0 + i];
        __syncthreads();
        if (t < 216) {
            int i = 0;
            for (; i + 4 <= cnt; i += 4) {
                int i0 = use_e ? (p0 + i)     : sl_[i];
                int i1 = use_e ? (p0 + i + 1) : sl_[i+1];
                int i2 = use_e ? (p0 + i + 2) : sl_[i+2];
                int i3 = use_e ? (p0 + i + 3) : sl_[i+3];
                float4 v0 = *(const float4*)(base + (long)i0 * scale);
                float4 v1 = *(const float4*)(base + (long)i1 * scale);
                float4 v2 = *(const float4*)(base + (long)i2 * scale);
                float4 v3 = *(const float4*)(base + (long)i3 * scale);
                float w0 = al[i * 12 + hk];
                float w1 = al[(i+1) * 12 + hk];
                float w2 = al[(i+2) * 12 + hk];
                float w3 = al[(i+3) * 12 + hk];
                acc.x = fmaf(w0, v0.x, acc.x); acc.y = fmaf(w0, v0.y, acc.y);
                acc.z = fmaf(w0, v0.z, acc.z); acc.w = fmaf(w0, v0.w, acc.w);
                acc.x = fmaf(w1, v1.x, acc.x); acc.y = fmaf(w1, v1.y, acc.y);
                acc.z = fmaf(w1, v1.z, acc.z); acc.w = fmaf(w1, v1.w, acc.w);
                acc.x = fmaf(w2, v2.x, acc.x); acc.y = fmaf(w2, v2.y, acc.y);
                acc.z = fmaf(w2, v2.z, acc.z); acc.w = fmaf(w2, v2.w, acc.w);
                acc.x = fmaf(w3, v3.x, acc.x); acc.y = fmaf(w3, v3.y, acc.y);
                acc.z = fmaf(w3, v3.z, acc.z); acc.w = fmaf(w3, v3.w, acc.w);
            }
            for (; i < cnt; i++) {
                int ii = use_e ? (p0 + i) : sl_[i];
                float4 v = *(const float4*)(base + (long)ii * scale);
                float w = al[i * 12 + hk];
                acc.x = fmaf(w, v.x, acc.x); acc.y = fmaf(w, v.y, acc.y);
                acc.z = fmaf(w, v.z, acc.z); acc.w = fmaf(w, v.w, acc.w);
            }
        }
    }
    if (t < 216) *(float4*)(agg + (long)n * AGG_D + comp) = acc;
}

// ---- feature build: inverse-rotate o_pt, norms, pack feats[10000][960] ----
#define NT_F 8
__global__ __launch_bounds__(192) void k_feat(const float* __restrict__ agg,
    const float* __restrict__ rot, const float* __restrict__ trans,
    float* __restrict__ feats) {
    int t = threadIdx.x;
    int node0 = blockIdx.x * NT_F;
    for (int idx = t; idx < NT_F * 192; idx += 192) {
        int nt = idx / 192, c = idx % 192;
        feats[(long)(node0 + nt) * FEAT_D + c] = agg[(long)(node0 + nt) * AGG_D + c];
    }
    for (int idx = t; idx < NT_F * 96; idx += 192) {
        int nt = idx / 96, p = idx % 96;
        int n = node0 + nt;
        const float* a = agg + (long)n * AGG_D;
        float gx = a[192 + p * 3 + 0] - trans[n * 3 + 0];
        float gy = a[192 + p * 3 + 1] - trans[n * 3 + 1];
        float gz = a[192 + p * 3 + 2] - trans[n * 3 + 2];
        const float* R = rot + (long)n * 9;
        float lx = R[0] * gx + R[3] * gy + R[6] * gz;
        float ly = R[1] * gx + R[4] * gy + R[7] * gz;
        float lz = R[2] * gx + R[5] * gy + R[8] * gz;
        float* f = feats + (long)n * FEAT_D;
        f[192 + p] = lx;
        f[288 + p] = ly;
        f[384 + p] = lz;
        f[480 + p] = sqrtf(lx * lx + ly * ly + lz * lz + 1e-8f);
    }
    for (int idx = t; idx < NT_F * 384; idx += 192) {
        int nt = idx / 384, q = idx % 384;
        feats[(long)(node0 + nt) * FEAT_D + 576 + q] =
            agg[(long)(node0 + nt) * AGG_D + 480 + q];
    }
}

// ---- output GEMM: [10000 x 960] @ wout[960 x 384] + bout, async-STAGE ----
__global__ __launch_bounds__(256) void k_out(const float* __restrict__ feats,
    const float* __restrict__ wout, const float* __restrict__ bout,
    float* __restrict__ out) {
    __shared__ float sT[BK][BM + 4];
    __shared__ float wt[BK][BN];
    int t = threadIdx.x;
    int bm0 = blockIdx.x * BM;
    int bn0 = blockIdx.y * BN;
    int tcol = t & 31;
    int trow = t >> 5;
    int c0 = tcol * 4;
    int r0 = trow * 8;

    int srow = t >> 2;
    int skoff = (t & 3) * 8;
    int gsrow = min(bm0 + srow, N_RESC - 1);
    const float* srcp = feats + (long)gsrow * FEAT_D + skoff;
    int wrow = t >> 5;
    const float* wp = wout + (long)wrow * OUT_D + bn0 + c0;

    float acc[8][4];
    #pragma unroll
    for (int i = 0; i < 8; i++)
        #pragma unroll
        for (int j = 0; j < 4; j++) acc[i][j] = 0.f;

    float4 sa = *(const float4*)(srcp + 0);
    float4 sb = *(const float4*)(srcp + 4);
    float4 wv0 = *(const float4*)(wp + 0 * 8 * OUT_D);
    float4 wv1 = *(const float4*)(wp + 1 * 8 * OUT_D);
    float4 wv2 = *(const float4*)(wp + 2 * 8 * OUT_D);
    float4 wv3 = *(const float4*)(wp + 3 * 8 * OUT_D);

    for (int k0 = 0; k0 < FEAT_D; k0 += BK) {
        sT[skoff + 0][srow] = sa.x; sT[skoff + 1][srow] = sa.y;
        sT[skoff + 2][srow] = sa.z; sT[skoff + 3][srow] = sa.w;
        sT[skoff + 4][srow] = sb.x; sT[skoff + 5][srow] = sb.y;
        sT[skoff + 6][srow] = sb.z; sT[skoff + 7][srow] = sb.w;
        *(float4*)&wt[wrow + 0 * 8][c0] = wv0;
        *(float4*)&wt[wrow + 1 * 8][c0] = wv1;
        *(float4*)&wt[wrow + 2 * 8][c0] = wv2;
        *(float4*)&wt[wrow + 3 * 8][c0] = wv3;
        __syncthreads();
        if (k0 + BK < FEAT_D) {
            sa = *(const float4*)(srcp + k0 + BK);
            sb = *(const float4*)(srcp + k0 + BK + 4);
            const float* wpn = wp + (long)(k0 + BK) * OUT_D;
            wv0 = *(const float4*)(wpn + 0 * 8 * OUT_D);
            wv1 = *(const float4*)(wpn + 1 * 8 * OUT_D);
            wv2 = *(const float4*)(wpn + 2 * 8 * OUT_D);
            wv3 = *(const float4*)(wpn + 3 * 8 * OUT_D);
        }
        #pragma unroll
        for (int k = 0; k < BK; k++) {
            float4 a0 = *(const float4*)&sT[k][r0];
            float4 a1 = *(const float4*)&sT[k][r0 + 4];
            float4 b  = *(const float4*)&wt[k][c0];
            float av0 = a0.x, av1 = a0.y, av2 = a0.z, av3 = a0.w;
            float av4 = a1.x, av5 = a1.y, av6 = a1.z, av7 = a1.w;
            acc[0][0] = fmaf(av0, b.x, acc[0][0]); acc[0][1] = fmaf(av0, b.y, acc[0][1]);
            acc[0][2] = fmaf(av0, b.z, acc[0][2]); acc[0][3] = fmaf(av0, b.w, acc[0][3]);
            acc[1][0] = fmaf(av1, b.x, acc[1][0]); acc[1][1] = fmaf(av1, b.y, acc[1][1]);
            acc[1][2] = fmaf(av1, b.z, acc[1][2]); acc[1][3] = fmaf(av1, b.w, acc[1][3]);
            acc[2][0] = fmaf(av2, b.x, acc[2][0]); acc[2][1] = fmaf(av2, b.y, acc[2][1]);
            acc[2][2] = fmaf(av2, b.z, acc[2][2]); acc[2][3] = fmaf(av2, b.w, acc[2][3]);
            acc[3][0] = fmaf(av3, b.x, acc[3][0]); acc[3][1] = fmaf(av3, b.y, acc[3][1]);
            acc[3][2] = fmaf(av3, b.z, acc[3][2]); acc[3][3] = fmaf(av3, b.w, acc[3][3]);
            acc[4][0] = fmaf(av4, b.x, acc[4][0]); acc[4][1] = fmaf(av4, b.y, acc[4][1]);
            acc[4][2] = fmaf(av4, b.z, acc[4][2]); acc[4][3] = fmaf(av4, b.w, acc[4][3]);
            acc[5][0] = fmaf(av5, b.x, acc[5][0]); acc[5][1] = fmaf(av5, b.y, acc[5][1]);
            acc[5][2] = fmaf(av5, b.z, acc[5][2]); acc[5][3] = fmaf(av5, b.w, acc[5][3]);
            acc[6][0] = fmaf(av6, b.x, acc[6][0]); acc[6][1] = fmaf(av6, b.y, acc[6][1]);
            acc[6][2] = fmaf(av6, b.z, acc[6][2]); acc[6][3] = fmaf(av6, b.w, acc[6][3]);
            acc[7][0] = fmaf(av7, b.x, acc[7][0]); acc[7][1] = fmaf(av7, b.y, acc[7][1]);
            acc[7][2] = fmaf(av7, b.z, acc[7][2]); acc[7][3] = fmaf(av7, b.w, acc[7][3]);
        }
        __syncthreads();
    }
    float bv0 = bout[bn0 + c0 + 0];
    float bv1 = bout[bn0 + c0 + 1];
    float bv2 = bout[bn0 + c0 + 2];
    float bv3 = bout[bn0 + c0 + 3];
    #pragma unroll
    for (int i = 0; i < 8; i++) {
        int n = bm0 + r0 + i;
        if (n < N_RESC) {
            *(float4*)(out + (long)n * OUT_D + bn0 + c0) =
                make_float4(acc[i][0] + bv0, acc[i][1] + bv1,
                            acc[i][2] + bv2, acc[i][3] + bv3);
        }
    }
}

extern "C" void kernel_launch(void* const* d_in, const int* in_sizes, int n_in,
                              void* d_out, int out_size, void* d_ws, size_t ws_size,
                              hipStream_t stream) {
    const float* s     = (const float*)d_in[0];
    const float* z     = (const float*)d_in[1];
    const float* rot   = (const float*)d_in[2];
    const float* trans = (const float*)d_in[3];
    const float* mask  = (const float*)d_in[4];
    const int*   ei    = (const int*)d_in[5];
    const float* wq    = (const float*)d_in[6];
    const float* bq    = (const float*)d_in[7];
    const float* wkv   = (const float*)d_in[8];
    const float* bkv   = (const float*)d_in[9];
    const float* wqp   = (const float*)d_in[10];
    const float* bqp   = (const float*)d_in[11];
    const float* wkvp  = (const float*)d_in[12];
    const float* bkvp  = (const float*)d_in[13];
    const float* wb    = (const float*)d_in[14];
    const float* bb    = (const float*)d_in[15];
    const float* wdz   = (const float*)d_in[16];
    const float* bdz   = (const float*)d_in[17];
    const float* head_w= (const float*)d_in[18];
    const float* wout  = (const float*)d_in[19];
    const float* bout  = (const float*)d_in[20];
    float* out = (float*)d_out;

    float* ws    = (float*)d_ws;
    float* qh    = ws;                         // 1,920,000
    float* kh    = qh + 1920000;               // 1,920,000
    float* vh    = kh + 1920000;               // 1,920,000
    float* qpts  = vh + 1920000;               // 1,440,000
    float* kpts  = qpts + 1440000;             // 1,440,000
    float* vpts  = kpts + 1440000;             // 2,880,000
    float* b_e   = vpts + 2880000;             // 3,840,000  (CSR order)
    float* pairz = b_e + 3840000;              // 10,240,000 (CSR order)
    float* alog  = pairz + 10240000;           // 3,840,000
    float* agg   = alog + 3840000;             // 8,640,000
    float* praw  = agg;                        // alias: praw (5.76M floats) inside agg region
    float* wpack = agg + 5760000;              // alias: 442,368 floats
    float* bpack = wpack + 442368;             // alias: 1,152 floats
    float* wzpack= bpack + 1152;               // alias: 6,144 floats
    float* bzpack= wzpack + 6144;              // alias: 48 floats (total < 8.64M)
    float* feats = pairz;                      // alias: 9.6M floats in pairz region
                                               // (pairz dead after k_agg)
    int* rowptr  = (int*)(agg + 8640000);      // 10001 (+pad)
    int* cursor  = rowptr + 10004;
    int* csr     = cursor + 10000;
    int* src_csr = csr + N_EDGEC;
    int* epos    = src_csr + N_EDGEC;

    // CSR build by dst
    k_zero<<<(N_RESC + 255) / 256, 256, 0, stream>>>(cursor);
    k_hist<<<(N_EDGEC + 255) / 256, 256, 0, stream>>>(ei, cursor);
    k_scan<<<1, 1024, 0, stream>>>(cursor, rowptr);
    k_scatter<<<(N_EDGEC + 255) / 256, 256, 0, stream>>>(ei, cursor, csr, src_csr, epos);

    // weight repack (proj + zproj), then tiled projection GEMM
    k_wpack<<<(384 * 1152 + 255) / 256, 256, 0, stream>>>(wq, bq, wkv, bkv, wqp, bqp,
                                                          wkvp, bkvp, wb, bb, wdz, bdz,
                                                          wpack, bpack, wzpack, bzpack);
    dim3 pgrid((N_RESC + BM - 1) / BM, 1152 / BN);
    k_proj<<<pgrid, 256, 0, stream>>>(s, wpack, bpack, qh, kh, vh, praw);
    k_rot<<<N_RESC, 192, 0, stream>>>(praw, rot, trans, qpts, kpts, vpts);

    // edge z-projection: tiled GEMM, contiguous z reads, CSR-scattered outputs
    k_zproj<<<N_EDGEC / ZBM, 256, 0, stream>>>(z, epos, wzpack, bzpack, b_e, pairz);

    // logits in CSR order
    k_logit<<<N_RESC, 256, 0, stream>>>(rowptr, src_csr, qh, kh, qpts, kpts,
                                        mask, head_w, b_e, alog);

    // per-node softmax + aggregation
    k_agg<<<N_RESC, 256, 0, stream>>>(rowptr, src_csr, alog, vh, vpts, pairz, agg);

    // feature build (pairz dead -> feats aliases it), then output GEMM
    k_feat<<<N_RESC / NT_F, 192, 0, stream>>>(agg, rot, trans, feats);
    dim3 ogrid((N_RESC + BM - 1) / BM, OUT_D / BN);
    k_out<<<ogrid, 256, 0, stream>>>(feats, wout, bout, out);
}

// Round 7
// 767.095 us; speedup vs baseline: 1.0387x; 1.0387x over previous
//
#include <hip/hip_runtime.h>
#include <hip/hip_bf16.h>
#include <math.h>

#define N_RESC 10000
#define N_EDGEC 320000
#define C_SC 384
#define C_ZC 128
#define AGG_D 864
#define FEAT_D 960
#define OUT_D 384

// scales
#define S1C 0.14433756729740643f   /* sqrt(1/48) */
#define S2C 0.5773502691896258f    /* sqrt(1/3)  */
#define SHWC 0.13608276348795434f  /* sqrt(1/54) */

__global__ void k_zero(int* cursor) {
    int i = blockIdx.x * 256 + threadIdx.x;
    if (i < N_RESC) cursor[i] = 0;
}

__global__ void k_hist(const int* __restrict__ ei, int* cursor) {
    int e = blockIdx.x * 256 + threadIdx.x;
    if (e < N_EDGEC) atomicAdd(&cursor[ei[N_EDGEC + e]], 1);
}

__global__ __launch_bounds__(1024) void k_scan(int* cursor, int* rowptr) {
    __shared__ int buf[1024];
    __shared__ int carry_s;
    int t = threadIdx.x;
    if (t == 0) carry_s = 0;
    __syncthreads();
    for (int ch = 0; ch < 10; ++ch) {
        int idx = ch * 1024 + t;
        int v = (idx < N_RESC) ? cursor[idx] : 0;
        buf[t] = v;
        __syncthreads();
        for (int off = 1; off < 1024; off <<= 1) {
            int x = (t >= off) ? buf[t - off] : 0;
            __syncthreads();
            buf[t] += x;
            __syncthreads();
        }
        int incl = buf[t];
        int excl = incl - v;
        int base = carry_s;
        int total = buf[1023];
        if (idx < N_RESC) { rowptr[idx] = base + excl; cursor[idx] = base + excl; }
        __syncthreads();
        if (t == 0) carry_s = base + total;
        __syncthreads();
    }
    if (t == 0) rowptr[N_RESC] = carry_s;
}

// also records inverse permutation epos[e] = CSR position
__global__ void k_scatter(const int* __restrict__ ei, int* cursor, int* csr,
                          int* src_csr, int* epos) {
    int e = blockIdx.x * 256 + threadIdx.x;
    if (e < N_EDGEC) {
        int d = ei[N_EDGEC + e];
        int s = ei[e];
        int pos = atomicAdd(&cursor[d], 1);
        csr[pos] = e;
        src_csr[pos] = s;
        epos[e] = pos;
    }
}

// ---- repack projection weights [384][1152] + z-proj weights [128][48] ----
// wpack col map: [0,192)=wq | [192,576)=wkv | [576,720)=wqp | [720,1152)=wkvp
// wzpack col map: [0,12)=wb | [12,44)=wdz | [44,48)=zero pad
__global__ __launch_bounds__(256) void k_wpack(
    const float* __restrict__ wq, const float* __restrict__ bq,
    const float* __restrict__ wkv, const float* __restrict__ bkv,
    const float* __restrict__ wqp, const float* __restrict__ bqp,
    const float* __restrict__ wkvp, const float* __restrict__ bkvp,
    const float* __restrict__ wb, const float* __restrict__ bb,
    const float* __restrict__ wdz, const float* __restrict__ bdz,
    float* __restrict__ wpack, float* __restrict__ bpack,
    float* __restrict__ wzpack, float* __restrict__ bzpack) {
    int idx = blockIdx.x * 256 + threadIdx.x;
    if (idx < 384 * 1152) {
        int j = idx / 1152, c = idx % 1152;
        float v;
        if (c < 192)      v = wq[j * 192 + c];
        else if (c < 576) v = wkv[j * 384 + (c - 192)];
        else if (c < 720) v = wqp[j * 144 + (c - 576)];
        else              v = wkvp[j * 432 + (c - 720)];
        wpack[idx] = v;
    }
    if (idx < 1152) {
        float b;
        if (idx < 192)      b = bq[idx];
        else if (idx < 576) b = bkv[idx - 192];
        else if (idx < 720) b = bqp[idx - 576];
        else                b = bkvp[idx - 720];
        bpack[idx] = b;
    }
    if (idx < 128 * 48) {
        int j = idx / 48, c = idx % 48;
        float v = 0.f;
        if (c < 12)      v = wb[j * 12 + c];
        else if (c < 44) v = wdz[j * 32 + (c - 12)];
        wzpack[idx] = v;
    }
    if (idx < 48) {
        float b = 0.f;
        if (idx < 12)      b = bb[idx];
        else if (idx < 44) b = bdz[idx - 12];
        bzpack[idx] = b;
    }
}

// ---- node projections: tiled fp32 GEMM  [10000 x 384] @ [384 x 1152] ----
// (round-5 measured-best synchronous staging; async-STAGE variant regressed)
#define BM 64
#define BN 128
#define BK 32
__global__ __launch_bounds__(256) void k_proj(const float* __restrict__ s,
    const float* __restrict__ wpack, const float* __restrict__ bpack,
    float* __restrict__ qh, float* __restrict__ kh, float* __restrict__ vh,
    float* __restrict__ praw) {
    __shared__ float sT[BK][BM + 4];
    __shared__ float wt[BK][BN];
    int t = threadIdx.x;
    int bm0 = blockIdx.x * BM;
    int bn0 = blockIdx.y * BN;
    int tcol = t & 31;
    int trow = t >> 5;
    int c0 = tcol * 4;
    int r0 = trow * 8;

    int srow = t >> 2;
    int skoff = (t & 3) * 8;
    int gsrow = min(bm0 + srow, N_RESC - 1);
    const float* srcp = s + (long)gsrow * C_SC + skoff;

    float acc[8][4];
    #pragma unroll
    for (int i = 0; i < 8; i++)
        #pragma unroll
        for (int j = 0; j < 4; j++) acc[i][j] = 0.f;

    for (int k0 = 0; k0 < C_SC; k0 += BK) {
        float4 sa = *(const float4*)(srcp + k0);
        float4 sb = *(const float4*)(srcp + k0 + 4);
        sT[skoff + 0][srow] = sa.x; sT[skoff + 1][srow] = sa.y;
        sT[skoff + 2][srow] = sa.z; sT[skoff + 3][srow] = sa.w;
        sT[skoff + 4][srow] = sb.x; sT[skoff + 5][srow] = sb.y;
        sT[skoff + 6][srow] = sb.z; sT[skoff + 7][srow] = sb.w;
        #pragma unroll
        for (int q = 0; q < 4; q++) {
            int kk = (t >> 5) + q * 8;
            *(float4*)&wt[kk][c0] =
                *(const float4*)(wpack + (long)(k0 + kk) * 1152 + bn0 + c0);
        }
        __syncthreads();
        #pragma unroll
        for (int k = 0; k < BK; k++) {
            float4 a0 = *(const float4*)&sT[k][r0];
            float4 a1 = *(const float4*)&sT[k][r0 + 4];
            float4 b  = *(const float4*)&wt[k][c0];
            float av0 = a0.x, av1 = a0.y, av2 = a0.z, av3 = a0.w;
            float av4 = a1.x, av5 = a1.y, av6 = a1.z, av7 = a1.w;
            acc[0][0] = fmaf(av0, b.x, acc[0][0]); acc[0][1] = fmaf(av0, b.y, acc[0][1]);
            acc[0][2] = fmaf(av0, b.z, acc[0][2]); acc[0][3] = fmaf(av0, b.w, acc[0][3]);
            acc[1][0] = fmaf(av1, b.x, acc[1][0]); acc[1][1] = fmaf(av1, b.y, acc[1][1]);
            acc[1][2] = fmaf(av1, b.z, acc[1][2]); acc[1][3] = fmaf(av1, b.w, acc[1][3]);
            acc[2][0] = fmaf(av2, b.x, acc[2][0]); acc[2][1] = fmaf(av2, b.y, acc[2][1]);
            acc[2][2] = fmaf(av2, b.z, acc[2][2]); acc[2][3] = fmaf(av2, b.w, acc[2][3]);
            acc[3][0] = fmaf(av3, b.x, acc[3][0]); acc[3][1] = fmaf(av3, b.y, acc[3][1]);
            acc[3][2] = fmaf(av3, b.z, acc[3][2]); acc[3][3] = fmaf(av3, b.w, acc[3][3]);
            acc[4][0] = fmaf(av4, b.x, acc[4][0]); acc[4][1] = fmaf(av4, b.y, acc[4][1]);
            acc[4][2] = fmaf(av4, b.z, acc[4][2]); acc[4][3] = fmaf(av4, b.w, acc[4][3]);
            acc[5][0] = fmaf(av5, b.x, acc[5][0]); acc[5][1] = fmaf(av5, b.y, acc[5][1]);
            acc[5][2] = fmaf(av5, b.z, acc[5][2]); acc[5][3] = fmaf(av5, b.w, acc[5][3]);
            acc[6][0] = fmaf(av6, b.x, acc[6][0]); acc[6][1] = fmaf(av6, b.y, acc[6][1]);
            acc[6][2] = fmaf(av6, b.z, acc[6][2]); acc[6][3] = fmaf(av6, b.w, acc[6][3]);
            acc[7][0] = fmaf(av7, b.x, acc[7][0]); acc[7][1] = fmaf(av7, b.y, acc[7][1]);
            acc[7][2] = fmaf(av7, b.z, acc[7][2]); acc[7][3] = fmaf(av7, b.w, acc[7][3]);
        }
        __syncthreads();
    }
    #pragma unroll
    for (int j = 0; j < 4; j++) {
        int c = bn0 + c0 + j;
        float bv = bpack[c];
        #pragma unroll
        for (int i = 0; i < 8; i++) {
            int n = bm0 + r0 + i;
            if (n < N_RESC) {
                float val = acc[i][j] + bv;
                if (c < 192) qh[(long)n * 192 + c] = val;
                else if (c < 576) {
                    int cc = c - 192; int h = cc >> 5, r = cc & 31;
                    if (r < 16) kh[(long)n * 192 + h * 16 + r] = val;
                    else        vh[(long)n * 192 + h * 16 + (r - 16)] = val;
                } else praw[(long)n * 576 + (c - 576)] = val;
            }
        }
    }
}

// ---- rotate/translate raw point projections into global frame, split layouts ----
__global__ __launch_bounds__(192) void k_rot(const float* __restrict__ praw,
    const float* __restrict__ rot, const float* __restrict__ trans,
    float* __restrict__ qpts, float* __restrict__ kpts, float* __restrict__ vpts) {
    int n = blockIdx.x;
    int t = threadIdx.x;
    __shared__ float R[9], T[3];
    if (t < 9) R[t] = rot[n * 9 + t];
    if (t < 3) T[t] = trans[n * 3 + t];
    __syncthreads();
    const float* pr = praw + (long)n * 576;
    if (t < 48) {
        float x0 = pr[t], x1 = pr[48 + t], x2 = pr[96 + t];
        #pragma unroll
        for (int i = 0; i < 3; i++)
            qpts[(long)n * 144 + t * 3 + i] = R[i*3+0]*x0 + R[i*3+1]*x1 + R[i*3+2]*x2 + T[i];
    } else {
        int p = t - 48;
        float x0 = pr[144 + p], x1 = pr[288 + p], x2 = pr[432 + p];
        int h = p / 12, pp = p % 12;
        #pragma unroll
        for (int i = 0; i < 3; i++) {
            float val = R[i*3+0]*x0 + R[i*3+1]*x1 + R[i*3+2]*x2 + T[i];
            if (pp < 4) kpts[(long)n * 144 + (h * 4 + pp) * 3 + i] = val;
            else        vpts[(long)n * 288 + (h * 8 + (pp - 4)) * 3 + i] = val;
        }
    }
}

// ---- edge GEMM as tiled GEMM: [320000 x 128] @ [128 x 48(44)] ----
// (round-4 measured-best synchronous version)
#define ZBM 128
__global__ __launch_bounds__(256) void k_zproj(const float* __restrict__ z,
    const int* __restrict__ epos,
    const float* __restrict__ wzpack, const float* __restrict__ bzpack,
    float* __restrict__ b_e, float* __restrict__ pairz) {
    __shared__ float zT[32][ZBM + 4];
    __shared__ float wl[128][48];
    int t = threadIdx.x;
    long e0 = (long)blockIdx.x * ZBM;
    int er = t & 31;        // 4 edges: er*4 .. +3
    int cg = t >> 5;        // 6 cols:  cg*6 .. +5
    int cb = cg * 6;

    #pragma unroll
    for (int q = 0; q < 6; q++) {
        int f = t + q * 256;
        int row = f / 12, c4 = f % 12;
        *(float4*)&wl[row][c4 * 4] = *(const float4*)(wzpack + row * 48 + c4 * 4);
    }

    float acc[4][6];
    #pragma unroll
    for (int i = 0; i < 4; i++)
        #pragma unroll
        for (int j = 0; j < 6; j++) acc[i][j] = 0.f;

    int r = t >> 1, ch2 = t & 1;
    const float* zp = z + (e0 + r) * C_ZC + ch2 * 16;

    for (int kc = 0; kc < 4; kc++) {
        __syncthreads();
        #pragma unroll
        for (int q = 0; q < 4; q++) {
            float4 v = *(const float4*)(zp + kc * 32 + q * 4);
            int kk = ch2 * 16 + q * 4;
            zT[kk + 0][r] = v.x; zT[kk + 1][r] = v.y;
            zT[kk + 2][r] = v.z; zT[kk + 3][r] = v.w;
        }
        __syncthreads();
        #pragma unroll
        for (int k = 0; k < 32; k++) {
            float4 zv = *(const float4*)&zT[k][er * 4];
            const float* wrow = &wl[kc * 32 + k][cb];
            float w0 = wrow[0], w1 = wrow[1], w2 = wrow[2];
            float w3 = wrow[3], w4 = wrow[4], w5 = wrow[5];
            acc[0][0] = fmaf(zv.x, w0, acc[0][0]); acc[0][1] = fmaf(zv.x, w1, acc[0][1]);
            acc[0][2] = fmaf(zv.x, w2, acc[0][2]); acc[0][3] = fmaf(zv.x, w3, acc[0][3]);
            acc[0][4] = fmaf(zv.x, w4, acc[0][4]); acc[0][5] = fmaf(zv.x, w5, acc[0][5]);
            acc[1][0] = fmaf(zv.y, w0, acc[1][0]); acc[1][1] = fmaf(zv.y, w1, acc[1][1]);
            acc[1][2] = fmaf(zv.y, w2, acc[1][2]); acc[1][3] = fmaf(zv.y, w3, acc[1][3]);
            acc[1][4] = fmaf(zv.y, w4, acc[1][4]); acc[1][5] = fmaf(zv.y, w5, acc[1][5]);
            acc[2][0] = fmaf(zv.z, w0, acc[2][0]); acc[2][1] = fmaf(zv.z, w1, acc[2][1]);
            acc[2][2] = fmaf(zv.z, w2, acc[2][2]); acc[2][3] = fmaf(zv.z, w3, acc[2][3]);
            acc[2][4] = fmaf(zv.z, w4, acc[2][4]); acc[2][5] = fmaf(zv.z, w5, acc[2][5]);
            acc[3][0] = fmaf(zv.w, w0, acc[3][0]); acc[3][1] = fmaf(zv.w, w1, acc[3][1]);
            acc[3][2] = fmaf(zv.w, w2, acc[3][2]); acc[3][3] = fmaf(zv.w, w3, acc[3][3]);
            acc[3][4] = fmaf(zv.w, w4, acc[3][4]); acc[3][5] = fmaf(zv.w, w5, acc[3][5]);
        }
    }

    float bz0 = bzpack[cb + 0], bz1 = bzpack[cb + 1], bz2 = bzpack[cb + 2];
    float bz3 = bzpack[cb + 3], bz4 = bzpack[cb + 4], bz5 = bzpack[cb + 5];
    #pragma unroll
    for (int ei = 0; ei < 4; ei++) {
        long pos = epos[e0 + er * 4 + ei];
        float o0 = acc[ei][0] + bz0, o1 = acc[ei][1] + bz1;
        float o2 = acc[ei][2] + bz2, o3 = acc[ei][3] + bz3;
        float o4 = acc[ei][4] + bz4, o5 = acc[ei][5] + bz5;
        if (cb < 12) {
            float* d = b_e + pos * 12 + cb;
            *(float2*)(d + 0) = make_float2(o0, o1);
            *(float2*)(d + 2) = make_float2(o2, o3);
            *(float2*)(d + 4) = make_float2(o4, o5);
        } else if (cb < 42) {
            float* d = pairz + pos * 32 + (cb - 12);
            *(float2*)(d + 0) = make_float2(o0, o1);
            *(float2*)(d + 2) = make_float2(o2, o3);
            *(float2*)(d + 4) = make_float2(o4, o5);
        } else {
            *(float2*)(pairz + pos * 32 + 30) = make_float2(o0, o1);
        }
    }
}

// ---- FUSED attention: logits (LDS) + online softmax + aggregation ----
// Per node: chunk of <=256 edges; logits never touch global memory.
// alog buffer eliminated (was 15MB write + 61MB of reads across 2 kernels).
#define CAPA 256
__global__ __launch_bounds__(256) void k_attn(const int* __restrict__ rowptr,
    const int* __restrict__ src_csr,
    const float* __restrict__ qh, const float* __restrict__ kh,
    const float* __restrict__ qpts, const float* __restrict__ kpts,
    const float* __restrict__ mask, const float* __restrict__ head_w,
    const float* __restrict__ b_e,
    const float* __restrict__ vh, const float* __restrict__ vpts,
    const float* __restrict__ pairz,
    float* __restrict__ agg) {
    int n = blockIdx.x;
    int t = threadIdx.x;
    __shared__ float qf[192], qp[144], hws[12];
    __shared__ int slist[CAPA];
    __shared__ float al[CAPA * 12];
    __shared__ float red[16 * 12];
    __shared__ float mh[12], lh[12], rh[12];
    if (t < 192) qf[t] = qh[(long)n * 192 + t];
    if (t < 144) qp[t] = qpts[(long)n * 144 + t];
    if (t < 12) { hws[t] = log1pf(expf(head_w[t])) * SHWC; mh[t] = -1e30f; lh[t] = 0.f; }
    float mdst = mask[n];
    int row0 = rowptr[n];
    int deg = rowptr[n + 1] - row0;
    int w = t >> 6, l = t & 63, c = l & 15, hq = l >> 4;
    int g = t >> 4, l16 = t & 15;

    // aggregation mapping (216 threads cover 864 agg components as float4)
    const float* base = nullptr;
    int scale = 0, hk = 0, use_e = 0;
    int comp = t * 4;
    if (comp < 192)      { base = vh + comp; scale = 192; hk = comp >> 4; }
    else if (comp < 480) { int idx = comp - 192; base = vpts + idx; scale = 288; hk = idx / 24; }
    else if (comp < 864) { int idx = comp - 480; base = pairz + (idx & 31); scale = 32; hk = idx >> 5; use_e = 1; }
    float4 acc = make_float4(0.f, 0.f, 0.f, 0.f);

    for (int cs = 0; cs < deg; cs += CAPA) {
        int cnt = min(CAPA, deg - cs);
        int p0 = row0 + cs;
        __syncthreads();   // protect slist/al from previous chunk's aggregate
        for (int i = t; i < cnt; i += 256) slist[i] = src_csr[p0 + i];
        __syncthreads();
        // ---- logit phase: raw logits -> al[i*12+h] ----
        for (int i = w * 2; i < cnt; i += 8) {
            int i1 = min(i + 1, cnt - 1);
            int s0 = slist[i], s1 = slist[i1];
            float em0 = 100000.0f * (mask[s0] * mdst - 1.0f);
            float em1 = 100000.0f * (mask[s1] * mdst - 1.0f);
            float kv0[3], kv1[3];
            #pragma unroll
            for (int tp = 0; tp < 3; tp++) {
                kv0[tp] = kh[(long)s0 * 192 + tp * 64 + l];
                kv1[tp] = kh[(long)s1 * 192 + tp * 64 + l];
            }
            float kp0[3] = {0.f,0.f,0.f}, kp1[3] = {0.f,0.f,0.f};
            if (c < 12) {
                #pragma unroll
                for (int tp = 0; tp < 3; tp++) {
                    int h = tp * 4 + hq;
                    kp0[tp] = kpts[(long)s0 * 144 + h * 12 + c];
                    kp1[tp] = kpts[(long)s1 * 144 + h * 12 + c];
                }
            }
            float be0[3] = {0.f,0.f,0.f}, be1[3] = {0.f,0.f,0.f};
            if (c == 0) {
                #pragma unroll
                for (int tp = 0; tp < 3; tp++) {
                    int h = tp * 4 + hq;
                    be0[tp] = b_e[(long)(p0 + i) * 12 + h];
                    be1[tp] = b_e[(long)(p0 + i1) * 12 + h];
                }
            }
            #pragma unroll
            for (int tp = 0; tp < 3; tp++) {
                int h = tp * 4 + hq;
                float qfv = S1C * qf[h * 16 + c];
                float val0 = qfv * kv0[tp];
                float val1 = qfv * kv1[tp];
                if (c < 12) {
                    float qpv = qp[h * 12 + c];
                    float hw = -0.5f * hws[h];
                    float d0 = qpv - kp0[tp];
                    float d1 = qpv - kp1[tp];
                    val0 = fmaf(hw * d0, d0, val0);
                    val1 = fmaf(hw * d1, d1, val1);
                }
                val0 += __shfl_xor(val0, 8, 16); val1 += __shfl_xor(val1, 8, 16);
                val0 += __shfl_xor(val0, 4, 16); val1 += __shfl_xor(val1, 4, 16);
                val0 += __shfl_xor(val0, 2, 16); val1 += __shfl_xor(val1, 2, 16);
                val0 += __shfl_xor(val0, 1, 16); val1 += __shfl_xor(val1, 1, 16);
                if (c == 0) {
                    al[i * 12 + h] = val0 + S2C * be0[tp] + em0;
                    if (i1 != i)
                        al[i1 * 12 + h] = val1 + S2C * be1[tp] + em1;
                }
            }
        }
        __syncthreads();
        // ---- chunk max per head, merge into running max ----
        if (l16 < 12) {
            float lm = -1e30f;
            for (int i = g; i < cnt; i += 16) lm = fmaxf(lm, al[i * 12 + l16]);
            red[g * 12 + l16] = lm;
        }
        __syncthreads();
        if (t < 12) {
            float m = mh[t];
            for (int gg = 0; gg < 16; gg++) m = fmaxf(m, red[gg * 12 + t]);
            rh[t] = expf(mh[t] - m);   // first chunk: exp(-inf)=0, acc is 0 anyway
            mh[t] = m;
        }
        __syncthreads();
        // ---- exp conversion (unnormalized p) + chunk sums ----
        if (l16 < 12) {
            float m = mh[l16];
            float ls = 0.f;
            for (int i = g; i < cnt; i += 16) {
                float p = expf(al[i * 12 + l16] - m);
                al[i * 12 + l16] = p;
                ls += p;
            }
            red[g * 12 + l16] = ls;
        }
        __syncthreads();
        if (t < 12) {
            float ss = 0.f;
            for (int gg = 0; gg < 16; gg++) ss += red[gg * 12 + t];
            lh[t] = lh[t] * rh[t] + ss;
        }
        __syncthreads();
        // ---- aggregate chunk (rescale running acc by rh[hk]) ----
        if (t < 216) {
            float r = rh[hk];
            acc.x *= r; acc.y *= r; acc.z *= r; acc.w *= r;
            int i = 0;
            for (; i + 4 <= cnt; i += 4) {
                int i0 = use_e ? (p0 + i)     : slist[i];
                int i1 = use_e ? (p0 + i + 1) : slist[i+1];
                int i2 = use_e ? (p0 + i + 2) : slist[i+2];
                int i3 = use_e ? (p0 + i + 3) : slist[i+3];
                float4 v0 = *(const float4*)(base + (long)i0 * scale);
                float4 v1 = *(const float4*)(base + (long)i1 * scale);
                float4 v2 = *(const float4*)(base + (long)i2 * scale);
                float4 v3 = *(const float4*)(base + (long)i3 * scale);
                float w0 = al[i * 12 + hk];
                float w1 = al[(i+1) * 12 + hk];
                float w2 = al[(i+2) * 12 + hk];
                float w3 = al[(i+3) * 12 + hk];
                acc.x = fmaf(w0, v0.x, acc.x); acc.y = fmaf(w0, v0.y, acc.y);
                acc.z = fmaf(w0, v0.z, acc.z); acc.w = fmaf(w0, v0.w, acc.w);
                acc.x = fmaf(w1, v1.x, acc.x); acc.y = fmaf(w1, v1.y, acc.y);
                acc.z = fmaf(w1, v1.z, acc.z); acc.w = fmaf(w1, v1.w, acc.w);
                acc.x = fmaf(w2, v2.x, acc.x); acc.y = fmaf(w2, v2.y, acc.y);
                acc.z = fmaf(w2, v2.z, acc.z); acc.w = fmaf(w2, v2.w, acc.w);
                acc.x = fmaf(w3, v3.x, acc.x); acc.y = fmaf(w3, v3.y, acc.y);
                acc.z = fmaf(w3, v3.z, acc.z); acc.w = fmaf(w3, v3.w, acc.w);
            }
            for (; i < cnt; i++) {
                int ii = use_e ? (p0 + i) : slist[i];
                float4 v = *(const float4*)(base + (long)ii * scale);
                float wv = al[i * 12 + hk];
                acc.x = fmaf(wv, v.x, acc.x); acc.y = fmaf(wv, v.y, acc.y);
                acc.z = fmaf(wv, v.z, acc.z); acc.w = fmaf(wv, v.w, acc.w);
            }
        }
    }
    if (t < 216) {
        float linv = 1.f / (lh[hk] + 1e-16f);
        acc.x *= linv; acc.y *= linv; acc.z *= linv; acc.w *= linv;
        *(float4*)(agg + (long)n * AGG_D + comp) = acc;
    }
}

// ---- feature build: inverse-rotate o_pt, norms, pack feats[10000][960] ----
#define NT_F 8
__global__ __launch_bounds__(192) void k_feat(const float* __restrict__ agg,
    const float* __restrict__ rot, const float* __restrict__ trans,
    float* __restrict__ feats) {
    int t = threadIdx.x;
    int node0 = blockIdx.x * NT_F;
    for (int idx = t; idx < NT_F * 192; idx += 192) {
        int nt = idx / 192, c = idx % 192;
        feats[(long)(node0 + nt) * FEAT_D + c] = agg[(long)(node0 + nt) * AGG_D + c];
    }
    for (int idx = t; idx < NT_F * 96; idx += 192) {
        int nt = idx / 96, p = idx % 96;
        int n = node0 + nt;
        const float* a = agg + (long)n * AGG_D;
        float gx = a[192 + p * 3 + 0] - trans[n * 3 + 0];
        float gy = a[192 + p * 3 + 1] - trans[n * 3 + 1];
        float gz = a[192 + p * 3 + 2] - trans[n * 3 + 2];
        const float* R = rot + (long)n * 9;
        float lx = R[0] * gx + R[3] * gy + R[6] * gz;
        float ly = R[1] * gx + R[4] * gy + R[7] * gz;
        float lz = R[2] * gx + R[5] * gy + R[8] * gz;
        float* f = feats + (long)n * FEAT_D;
        f[192 + p] = lx;
        f[288 + p] = ly;
        f[384 + p] = lz;
        f[480 + p] = sqrtf(lx * lx + ly * ly + lz * lz + 1e-8f);
    }
    for (int idx = t; idx < NT_F * 384; idx += 192) {
        int nt = idx / 384, q = idx % 384;
        feats[(long)(node0 + nt) * FEAT_D + 576 + q] =
            agg[(long)(node0 + nt) * AGG_D + 480 + q];
    }
}

// ---- output GEMM: [10000 x 960] @ wout[960 x 384] + bout (sync staging) ----
__global__ __launch_bounds__(256) void k_out(const float* __restrict__ feats,
    const float* __restrict__ wout, const float* __restrict__ bout,
    float* __restrict__ out) {
    __shared__ float sT[BK][BM + 4];
    __shared__ float wt[BK][BN];
    int t = threadIdx.x;
    int bm0 = blockIdx.x * BM;
    int bn0 = blockIdx.y * BN;
    int tcol = t & 31;
    int trow = t >> 5;
    int c0 = tcol * 4;
    int r0 = trow * 8;

    int srow = t >> 2;
    int skoff = (t & 3) * 8;
    int gsrow = min(bm0 + srow, N_RESC - 1);
    const float* srcp = feats + (long)gsrow * FEAT_D + skoff;

    float acc[8][4];
    #pragma unroll
    for (int i = 0; i < 8; i++)
        #pragma unroll
        for (int j = 0; j < 4; j++) acc[i][j] = 0.f;

    for (int k0 = 0; k0 < FEAT_D; k0 += BK) {
        float4 sa = *(const float4*)(srcp + k0);
        float4 sb = *(const float4*)(srcp + k0 + 4);
        sT[skoff + 0][srow] = sa.x; sT[skoff + 1][srow] = sa.y;
        sT[skoff + 2][srow] = sa.z; sT[skoff + 3][srow] = sa.w;
        sT[skoff + 4][srow] = sb.x; sT[skoff + 5][srow] = sb.y;
        sT[skoff + 6][srow] = sb.z; sT[skoff + 7][srow] = sb.w;
        #pragma unroll
        for (int q = 0; q < 4; q++) {
            int kk = (t >> 5) + q * 8;
            *(float4*)&wt[kk][c0] =
                *(const float4*)(wout + (long)(k0 + kk) * OUT_D + bn0 + c0);
        }
        __syncthreads();
        #pragma unroll
        for (int k = 0; k < BK; k++) {
            float4 a0 = *(const float4*)&sT[k][r0];
            float4 a1 = *(const float4*)&sT[k][r0 + 4];
            float4 b  = *(const float4*)&wt[k][c0];
            float av0 = a0.x, av1 = a0.y, av2 = a0.z, av3 = a0.w;
            float av4 = a1.x, av5 = a1.y, av6 = a1.z, av7 = a1.w;
            acc[0][0] = fmaf(av0, b.x, acc[0][0]); acc[0][1] = fmaf(av0, b.y, acc[0][1]);
            acc[0][2] = fmaf(av0, b.z, acc[0][2]); acc[0][3] = fmaf(av0, b.w, acc[0][3]);
            acc[1][0] = fmaf(av1, b.x, acc[1][0]); acc[1][1] = fmaf(av1, b.y, acc[1][1]);
            acc[1][2] = fmaf(av1, b.z, acc[1][2]); acc[1][3] = fmaf(av1, b.w, acc[1][3]);
            acc[2][0] = fmaf(av2, b.x, acc[2][0]); acc[2][1] = fmaf(av2, b.y, acc[2][1]);
            acc[2][2] = fmaf(av2, b.z, acc[2][2]); acc[2][3] = fmaf(av2, b.w, acc[2][3]);
            acc[3][0] = fmaf(av3, b.x, acc[3][0]); acc[3][1] = fmaf(av3, b.y, acc[3][1]);
            acc[3][2] = fmaf(av3, b.z, acc[3][2]); acc[3][3] = fmaf(av3, b.w, acc[3][3]);
            acc[4][0] = fmaf(av4, b.x, acc[4][0]); acc[4][1] = fmaf(av4, b.y, acc[4][1]);
            acc[4][2] = fmaf(av4, b.z, acc[4][2]); acc[4][3] = fmaf(av4, b.w, acc[4][3]);
            acc[5][0] = fmaf(av5, b.x, acc[5][0]); acc[5][1] = fmaf(av5, b.y, acc[5][1]);
            acc[5][2] = fmaf(av5, b.z, acc[5][2]); acc[5][3] = fmaf(av5, b.w, acc[5][3]);
            acc[6][0] = fmaf(av6, b.x, acc[6][0]); acc[6][1] = fmaf(av6, b.y, acc[6][1]);
            acc[6][2] = fmaf(av6, b.z, acc[6][2]); acc[6][3] = fmaf(av6, b.w, acc[6][3]);
            acc[7][0] = fmaf(av7, b.x, acc[7][0]); acc[7][1] = fmaf(av7, b.y, acc[7][1]);
            acc[7][2] = fmaf(av7, b.z, acc[7][2]); acc[7][3] = fmaf(av7, b.w, acc[7][3]);
        }
        __syncthreads();
    }
    float bv0 = bout[bn0 + c0 + 0];
    float bv1 = bout[bn0 + c0 + 1];
    float bv2 = bout[bn0 + c0 + 2];
    float bv3 = bout[bn0 + c0 + 3];
    #pragma unroll
    for (int i = 0; i < 8; i++) {
        int n = bm0 + r0 + i;
        if (n < N_RESC) {
            *(float4*)(out + (long)n * OUT_D + bn0 + c0) =
                make_float4(acc[i][0] + bv0, acc[i][1] + bv1,
                            acc[i][2] + bv2, acc[i][3] + bv3);
        }
    }
}

extern "C" void kernel_launch(void* const* d_in, const int* in_sizes, int n_in,
                              void* d_out, int out_size, void* d_ws, size_t ws_size,
                              hipStream_t stream) {
    const float* s     = (const float*)d_in[0];
    const float* z     = (const float*)d_in[1];
    const float* rot   = (const float*)d_in[2];
    const float* trans = (const float*)d_in[3];
    const float* mask  = (const float*)d_in[4];
    const int*   ei    = (const int*)d_in[5];
    const float* wq    = (const float*)d_in[6];
    const float* bq    = (const float*)d_in[7];
    const float* wkv   = (const float*)d_in[8];
    const float* bkv   = (const float*)d_in[9];
    const float* wqp   = (const float*)d_in[10];
    const float* bqp   = (const float*)d_in[11];
    const float* wkvp  = (const float*)d_in[12];
    const float* bkvp  = (const float*)d_in[13];
    const float* wb    = (const float*)d_in[14];
    const float* bb    = (const float*)d_in[15];
    const float* wdz   = (const float*)d_in[16];
    const float* bdz   = (const float*)d_in[17];
    const float* head_w= (const float*)d_in[18];
    const float* wout  = (const float*)d_in[19];
    const float* bout  = (const float*)d_in[20];
    float* out = (float*)d_out;

    float* ws    = (float*)d_ws;
    float* qh    = ws;                         // 1,920,000
    float* kh    = qh + 1920000;               // 1,920,000
    float* vh    = kh + 1920000;               // 1,920,000
    float* qpts  = vh + 1920000;               // 1,440,000
    float* kpts  = qpts + 1440000;             // 1,440,000
    float* vpts  = kpts + 1440000;             // 2,880,000
    float* b_e   = vpts + 2880000;             // 3,840,000  (CSR order)
    float* pairz = b_e + 3840000;              // 10,240,000 (CSR order)
    float* alog  = pairz + 10240000;           // 3,840,000 (now unused; kept for layout)
    float* agg   = alog + 3840000;             // 8,640,000
    float* praw  = agg;                        // alias: praw (5.76M floats) inside agg region
    float* wpack = agg + 5760000;              // alias: 442,368 floats
    float* bpack = wpack + 442368;             // alias: 1,152 floats
    float* wzpack= bpack + 1152;               // alias: 6,144 floats
    float* bzpack= wzpack + 6144;              // alias: 48 floats (total < 8.64M)
    float* feats = pairz;                      // alias: 9.6M floats in pairz region
                                               // (pairz dead after k_attn)
    int* rowptr  = (int*)(agg + 8640000);      // 10001 (+pad)
    int* cursor  = rowptr + 10004;
    int* csr     = cursor + 10000;
    int* src_csr = csr + N_EDGEC;
    int* epos    = src_csr + N_EDGEC;

    // CSR build by dst
    k_zero<<<(N_RESC + 255) / 256, 256, 0, stream>>>(cursor);
    k_hist<<<(N_EDGEC + 255) / 256, 256, 0, stream>>>(ei, cursor);
    k_scan<<<1, 1024, 0, stream>>>(cursor, rowptr);
    k_scatter<<<(N_EDGEC + 255) / 256, 256, 0, stream>>>(ei, cursor, csr, src_csr, epos);

    // weight repack (proj + zproj), then tiled projection GEMM
    k_wpack<<<(384 * 1152 + 255) / 256, 256, 0, stream>>>(wq, bq, wkv, bkv, wqp, bqp,
                                                          wkvp, bkvp, wb, bb, wdz, bdz,
                                                          wpack, bpack, wzpack, bzpack);
    dim3 pgrid((N_RESC + BM - 1) / BM, 1152 / BN);
    k_proj<<<pgrid, 256, 0, stream>>>(s, wpack, bpack, qh, kh, vh, praw);
    k_rot<<<N_RESC, 192, 0, stream>>>(praw, rot, trans, qpts, kpts, vpts);

    // edge z-projection: tiled GEMM, contiguous z reads, CSR-scattered outputs
    k_zproj<<<N_EDGEC / ZBM, 256, 0, stream>>>(z, epos, wzpack, bzpack, b_e, pairz);

    // fused logits + softmax + aggregation (alog eliminated)
    k_attn<<<N_RESC, 256, 0, stream>>>(rowptr, src_csr, qh, kh, qpts, kpts,
                                       mask, head_w, b_e, vh, vpts, pairz, agg);

    // feature build (pairz dead -> feats aliases it), then output GEMM
    k_feat<<<N_RESC / NT_F, 192, 0, stream>>>(agg, rot, trans, feats);
    dim3 ogrid((N_RESC + BM - 1) / BM, OUT_D / BN);
    k_out<<<ogrid, 256, 0, stream>>>(feats, wout, bout, out);
}

// Round 9
// 765.680 us; speedup vs baseline: 1.0406x; 1.0018x over previous
//
#include <hip/hip_runtime.h>
#include <hip/hip_bf16.h>
#include <math.h>

#define N_RESC 10000
#define N_EDGEC 320000
#define C_SC 384
#define C_ZC 128
#define AGG_D 864
#define FEAT_D 960
#define OUT_D 384

// scales
#define S1C 0.14433756729740643f   /* sqrt(1/48) */
#define S2C 0.5773502691896258f    /* sqrt(1/3)  */
#define SHWC 0.13608276348795434f  /* sqrt(1/54) */

__global__ void k_zero(int* cursor) {
    int i = blockIdx.x * 256 + threadIdx.x;
    if (i < N_RESC) cursor[i] = 0;
}

__global__ void k_hist(const int* __restrict__ ei, int* cursor) {
    int e = blockIdx.x * 256 + threadIdx.x;
    if (e < N_EDGEC) atomicAdd(&cursor[ei[N_EDGEC + e]], 1);
}

__global__ __launch_bounds__(1024) void k_scan(int* cursor, int* rowptr) {
    __shared__ int buf[1024];
    __shared__ int carry_s;
    int t = threadIdx.x;
    if (t == 0) carry_s = 0;
    __syncthreads();
    for (int ch = 0; ch < 10; ++ch) {
        int idx = ch * 1024 + t;
        int v = (idx < N_RESC) ? cursor[idx] : 0;
        buf[t] = v;
        __syncthreads();
        for (int off = 1; off < 1024; off <<= 1) {
            int x = (t >= off) ? buf[t - off] : 0;
            __syncthreads();
            buf[t] += x;
            __syncthreads();
        }
        int incl = buf[t];
        int excl = incl - v;
        int base = carry_s;
        int total = buf[1023];
        if (idx < N_RESC) { rowptr[idx] = base + excl; cursor[idx] = base + excl; }
        __syncthreads();
        if (t == 0) carry_s = base + total;
        __syncthreads();
    }
    if (t == 0) rowptr[N_RESC] = carry_s;
}

// also records inverse permutation epos[e] = CSR position
__global__ void k_scatter(const int* __restrict__ ei, int* cursor, int* csr,
                          int* src_csr, int* epos) {
    int e = blockIdx.x * 256 + threadIdx.x;
    if (e < N_EDGEC) {
        int d = ei[N_EDGEC + e];
        int s = ei[e];
        int pos = atomicAdd(&cursor[d], 1);
        csr[pos] = e;
        src_csr[pos] = s;
        epos[e] = pos;
    }
}

// ---- repack projection weights [384][1152] + z-proj weights [128][48] ----
__global__ __launch_bounds__(256) void k_wpack(
    const float* __restrict__ wq, const float* __restrict__ bq,
    const float* __restrict__ wkv, const float* __restrict__ bkv,
    const float* __restrict__ wqp, const float* __restrict__ bqp,
    const float* __restrict__ wkvp, const float* __restrict__ bkvp,
    const float* __restrict__ wb, const float* __restrict__ bb,
    const float* __restrict__ wdz, const float* __restrict__ bdz,
    float* __restrict__ wpack, float* __restrict__ bpack,
    float* __restrict__ wzpack, float* __restrict__ bzpack) {
    int idx = blockIdx.x * 256 + threadIdx.x;
    if (idx < 384 * 1152) {
        int j = idx / 1152, c = idx % 1152;
        float v;
        if (c < 192)      v = wq[j * 192 + c];
        else if (c < 576) v = wkv[j * 384 + (c - 192)];
        else if (c < 720) v = wqp[j * 144 + (c - 576)];
        else              v = wkvp[j * 432 + (c - 720)];
        wpack[idx] = v;
    }
    if (idx < 1152) {
        float b;
        if (idx < 192)      b = bq[idx];
        else if (idx < 576) b = bkv[idx - 192];
        else if (idx < 720) b = bqp[idx - 576];
        else                b = bkvp[idx - 720];
        bpack[idx] = b;
    }
    if (idx < 128 * 48) {
        int j = idx / 48, c = idx % 48;
        float v = 0.f;
        if (c < 12)      v = wb[j * 12 + c];
        else if (c < 44) v = wdz[j * 32 + (c - 12)];
        wzpack[idx] = v;
    }
    if (idx < 48) {
        float b = 0.f;
        if (idx < 12)      b = bb[idx];
        else if (idx < 44) b = bdz[idx - 12];
        bzpack[idx] = b;
    }
}

// ---- node projections: tiled fp32 GEMM  [10000 x 384] @ [384 x 1152] ----
#define BM 64
#define BN 128
#define BK 32
__global__ __launch_bounds__(256) void k_proj(const float* __restrict__ s,
    const float* __restrict__ wpack, const float* __restrict__ bpack,
    float* __restrict__ qh, float* __restrict__ kh, float* __restrict__ vh,
    float* __restrict__ praw) {
    __shared__ float sT[BK][BM + 4];
    __shared__ float wt[BK][BN];
    int t = threadIdx.x;
    int bm0 = blockIdx.x * BM;
    int bn0 = blockIdx.y * BN;
    int tcol = t & 31;
    int trow = t >> 5;
    int c0 = tcol * 4;
    int r0 = trow * 8;

    int srow = t >> 2;
    int skoff = (t & 3) * 8;
    int gsrow = min(bm0 + srow, N_RESC - 1);
    const float* srcp = s + (long)gsrow * C_SC + skoff;

    float acc[8][4];
    #pragma unroll
    for (int i = 0; i < 8; i++)
        #pragma unroll
        for (int j = 0; j < 4; j++) acc[i][j] = 0.f;

    for (int k0 = 0; k0 < C_SC; k0 += BK) {
        float4 sa = *(const float4*)(srcp + k0);
        float4 sb = *(const float4*)(srcp + k0 + 4);
        sT[skoff + 0][srow] = sa.x; sT[skoff + 1][srow] = sa.y;
        sT[skoff + 2][srow] = sa.z; sT[skoff + 3][srow] = sa.w;
        sT[skoff + 4][srow] = sb.x; sT[skoff + 5][srow] = sb.y;
        sT[skoff + 6][srow] = sb.z; sT[skoff + 7][srow] = sb.w;
        #pragma unroll
        for (int q = 0; q < 4; q++) {
            int kk = (t >> 5) + q * 8;
            *(float4*)&wt[kk][c0] =
                *(const float4*)(wpack + (long)(k0 + kk) * 1152 + bn0 + c0);
        }
        __syncthreads();
        #pragma unroll
        for (int k = 0; k < BK; k++) {
            float4 a0 = *(const float4*)&sT[k][r0];
            float4 a1 = *(const float4*)&sT[k][r0 + 4];
            float4 b  = *(const float4*)&wt[k][c0];
            float av0 = a0.x, av1 = a0.y, av2 = a0.z, av3 = a0.w;
            float av4 = a1.x, av5 = a1.y, av6 = a1.z, av7 = a1.w;
            acc[0][0] = fmaf(av0, b.x, acc[0][0]); acc[0][1] = fmaf(av0, b.y, acc[0][1]);
            acc[0][2] = fmaf(av0, b.z, acc[0][2]); acc[0][3] = fmaf(av0, b.w, acc[0][3]);
            acc[1][0] = fmaf(av1, b.x, acc[1][0]); acc[1][1] = fmaf(av1, b.y, acc[1][1]);
            acc[1][2] = fmaf(av1, b.z, acc[1][2]); acc[1][3] = fmaf(av1, b.w, acc[1][3]);
            acc[2][0] = fmaf(av2, b.x, acc[2][0]); acc[2][1] = fmaf(av2, b.y, acc[2][1]);
            acc[2][2] = fmaf(av2, b.z, acc[2][2]); acc[2][3] = fmaf(av2, b.w, acc[2][3]);
            acc[3][0] = fmaf(av3, b.x, acc[3][0]); acc[3][1] = fmaf(av3, b.y, acc[3][1]);
            acc[3][2] = fmaf(av3, b.z, acc[3][2]); acc[3][3] = fmaf(av3, b.w, acc[3][3]);
            acc[4][0] = fmaf(av4, b.x, acc[4][0]); acc[4][1] = fmaf(av4, b.y, acc[4][1]);
            acc[4][2] = fmaf(av4, b.z, acc[4][2]); acc[4][3] = fmaf(av4, b.w, acc[4][3]);
            acc[5][0] = fmaf(av5, b.x, acc[5][0]); acc[5][1] = fmaf(av5, b.y, acc[5][1]);
            acc[5][2] = fmaf(av5, b.z, acc[5][2]); acc[5][3] = fmaf(av5, b.w, acc[5][3]);
            acc[6][0] = fmaf(av6, b.x, acc[6][0]); acc[6][1] = fmaf(av6, b.y, acc[6][1]);
            acc[6][2] = fmaf(av6, b.z, acc[6][2]); acc[6][3] = fmaf(av6, b.w, acc[6][3]);
            acc[7][0] = fmaf(av7, b.x, acc[7][0]); acc[7][1] = fmaf(av7, b.y, acc[7][1]);
            acc[7][2] = fmaf(av7, b.z, acc[7][2]); acc[7][3] = fmaf(av7, b.w, acc[7][3]);
        }
        __syncthreads();
    }
    #pragma unroll
    for (int j = 0; j < 4; j++) {
        int c = bn0 + c0 + j;
        float bv = bpack[c];
        #pragma unroll
        for (int i = 0; i < 8; i++) {
            int n = bm0 + r0 + i;
            if (n < N_RESC) {
                float val = acc[i][j] + bv;
                if (c < 192) qh[(long)n * 192 + c] = val;
                else if (c < 576) {
                    int cc = c - 192; int h = cc >> 5, r = cc & 31;
                    if (r < 16) kh[(long)n * 192 + h * 16 + r] = val;
                    else        vh[(long)n * 192 + h * 16 + (r - 16)] = val;
                } else praw[(long)n * 576 + (c - 576)] = val;
            }
        }
    }
}

// ---- rotate/translate raw point projections into global frame, split layouts ----
__global__ __launch_bounds__(192) void k_rot(const float* __restrict__ praw,
    const float* __restrict__ rot, const float* __restrict__ trans,
    float* __restrict__ qpts, float* __restrict__ kpts, float* __restrict__ vpts) {
    int n = blockIdx.x;
    int t = threadIdx.x;
    __shared__ float R[9], T[3];
    if (t < 9) R[t] = rot[n * 9 + t];
    if (t < 3) T[t] = trans[n * 3 + t];
    __syncthreads();
    const float* pr = praw + (long)n * 576;
    if (t < 48) {
        float x0 = pr[t], x1 = pr[48 + t], x2 = pr[96 + t];
        #pragma unroll
        for (int i = 0; i < 3; i++)
            qpts[(long)n * 144 + t * 3 + i] = R[i*3+0]*x0 + R[i*3+1]*x1 + R[i*3+2]*x2 + T[i];
    } else {
        int p = t - 48;
        float x0 = pr[144 + p], x1 = pr[288 + p], x2 = pr[432 + p];
        int h = p / 12, pp = p % 12;
        #pragma unroll
        for (int i = 0; i < 3; i++) {
            float val = R[i*3+0]*x0 + R[i*3+1]*x1 + R[i*3+2]*x2 + T[i];
            if (pp < 4) kpts[(long)n * 144 + (h * 4 + pp) * 3 + i] = val;
            else        vpts[(long)n * 288 + (h * 8 + (pp - 4)) * 3 + i] = val;
        }
    }
}

// ---- edge GEMM as tiled GEMM: [320000 x 128] @ [128 x 48(44)] ----
#define ZBM 128
__global__ __launch_bounds__(256) void k_zproj(const float* __restrict__ z,
    const int* __restrict__ epos,
    const float* __restrict__ wzpack, const float* __restrict__ bzpack,
    float* __restrict__ b_e, float* __restrict__ pairz) {
    __shared__ float zT[32][ZBM + 4];
    __shared__ float wl[128][48];
    int t = threadIdx.x;
    long e0 = (long)blockIdx.x * ZBM;
    int er = t & 31;
    int cg = t >> 5;
    int cb = cg * 6;

    #pragma unroll
    for (int q = 0; q < 6; q++) {
        int f = t + q * 256;
        int row = f / 12, c4 = f % 12;
        *(float4*)&wl[row][c4 * 4] = *(const float4*)(wzpack + row * 48 + c4 * 4);
    }

    float acc[4][6];
    #pragma unroll
    for (int i = 0; i < 4; i++)
        #pragma unroll
        for (int j = 0; j < 6; j++) acc[i][j] = 0.f;

    int r = t >> 1, ch2 = t & 1;
    const float* zp = z + (e0 + r) * C_ZC + ch2 * 16;

    for (int kc = 0; kc < 4; kc++) {
        __syncthreads();
        #pragma unroll
        for (int q = 0; q < 4; q++) {
            float4 v = *(const float4*)(zp + kc * 32 + q * 4);
            int kk = ch2 * 16 + q * 4;
            zT[kk + 0][r] = v.x; zT[kk + 1][r] = v.y;
            zT[kk + 2][r] = v.z; zT[kk + 3][r] = v.w;
        }
        __syncthreads();
        #pragma unroll
        for (int k = 0; k < 32; k++) {
            float4 zv = *(const float4*)&zT[k][er * 4];
            const float* wrow = &wl[kc * 32 + k][cb];
            float w0 = wrow[0], w1 = wrow[1], w2 = wrow[2];
            float w3 = wrow[3], w4 = wrow[4], w5 = wrow[5];
            acc[0][0] = fmaf(zv.x, w0, acc[0][0]); acc[0][1] = fmaf(zv.x, w1, acc[0][1]);
            acc[0][2] = fmaf(zv.x, w2, acc[0][2]); acc[0][3] = fmaf(zv.x, w3, acc[0][3]);
            acc[0][4] = fmaf(zv.x, w4, acc[0][4]); acc[0][5] = fmaf(zv.x, w5, acc[0][5]);
            acc[1][0] = fmaf(zv.y, w0, acc[1][0]); acc[1][1] = fmaf(zv.y, w1, acc[1][1]);
            acc[1][2] = fmaf(zv.y, w2, acc[1][2]); acc[1][3] = fmaf(zv.y, w3, acc[1][3]);
            acc[1][4] = fmaf(zv.y, w4, acc[1][4]); acc[1][5] = fmaf(zv.y, w5, acc[1][5]);
            acc[2][0] = fmaf(zv.z, w0, acc[2][0]); acc[2][1] = fmaf(zv.z, w1, acc[2][1]);
            acc[2][2] = fmaf(zv.z, w2, acc[2][2]); acc[2][3] = fmaf(zv.z, w3, acc[2][3]);
            acc[2][4] = fmaf(zv.z, w4, acc[2][4]); acc[2][5] = fmaf(zv.z, w5, acc[2][5]);
            acc[3][0] = fmaf(zv.w, w0, acc[3][0]); acc[3][1] = fmaf(zv.w, w1, acc[3][1]);
            acc[3][2] = fmaf(zv.w, w2, acc[3][2]); acc[3][3] = fmaf(zv.w, w3, acc[3][3]);
            acc[3][4] = fmaf(zv.w, w4, acc[3][4]); acc[3][5] = fmaf(zv.w, w5, acc[3][5]);
        }
    }

    float bz0 = bzpack[cb + 0], bz1 = bzpack[cb + 1], bz2 = bzpack[cb + 2];
    float bz3 = bzpack[cb + 3], bz4 = bzpack[cb + 4], bz5 = bzpack[cb + 5];
    #pragma unroll
    for (int ei = 0; ei < 4; ei++) {
        long pos = epos[e0 + er * 4 + ei];
        float o0 = acc[ei][0] + bz0, o1 = acc[ei][1] + bz1;
        float o2 = acc[ei][2] + bz2, o3 = acc[ei][3] + bz3;
        float o4 = acc[ei][4] + bz4, o5 = acc[ei][5] + bz5;
        if (cb < 12) {
            float* d = b_e + pos * 12 + cb;
            *(float2*)(d + 0) = make_float2(o0, o1);
            *(float2*)(d + 2) = make_float2(o2, o3);
            *(float2*)(d + 4) = make_float2(o4, o5);
        } else if (cb < 42) {
            float* d = pairz + pos * 32 + (cb - 12);
            *(float2*)(d + 0) = make_float2(o0, o1);
            *(float2*)(d + 2) = make_float2(o2, o3);
            *(float2*)(d + 4) = make_float2(o4, o5);
        } else {
            *(float2*)(pairz + pos * 32 + 30) = make_float2(o0, o1);
        }
    }
}

// ---- FUSED attention + feature build ----
// logits in LDS + online softmax + aggregation + inverse-rotate/norm epilogue.
// Writes feats[n][960] directly; agg buffer and k_feat eliminated.
#define CAPA 64
__global__ __launch_bounds__(256) void k_attn(const int* __restrict__ rowptr,
    const int* __restrict__ src_csr,
    const float* __restrict__ qh, const float* __restrict__ kh,
    const float* __restrict__ qpts, const float* __restrict__ kpts,
    const float* __restrict__ mask, const float* __restrict__ head_w,
    const float* __restrict__ b_e,
    const float* __restrict__ vh, const float* __restrict__ vpts,
    const float* __restrict__ pairz,
    const float* __restrict__ rot, const float* __restrict__ trans,
    float* __restrict__ feats) {
    int n = blockIdx.x;
    int t = threadIdx.x;
    __shared__ float qf[192], qp[144], hws[12];
    __shared__ int slist[CAPA];
    __shared__ float al[CAPA * 12];
    __shared__ float red[16 * 12];
    __shared__ float mh[12], lh[12], rh[12];
    __shared__ float aggl[AGG_D];
    __shared__ float R[9], T[3];
    if (t < 192) qf[t] = qh[(long)n * 192 + t];
    if (t < 144) qp[t] = qpts[(long)n * 144 + t];
    if (t < 12) { hws[t] = log1pf(expf(head_w[t])) * SHWC; mh[t] = -1e30f; lh[t] = 0.f; }
    if (t >= 192 && t < 201) R[t - 192] = rot[(long)n * 9 + (t - 192)];
    if (t >= 204 && t < 207) T[t - 204] = trans[(long)n * 3 + (t - 204)];
    float mdst = mask[n];
    int row0 = rowptr[n];
    int deg = rowptr[n + 1] - row0;
    int w = t >> 6, l = t & 63, c = l & 15, hq = l >> 4;
    int g = t >> 4, l16 = t & 15;

    // aggregation mapping (216 threads cover 864 agg components as float4)
    const float* base = nullptr;
    int scale = 0, hk = 0, use_e = 0;
    int comp = t * 4;
    if (comp < 192)      { base = vh + comp; scale = 192; hk = comp >> 4; }
    else if (comp < 480) { int idx = comp - 192; base = vpts + idx; scale = 288; hk = idx / 24; }
    else if (comp < 864) { int idx = comp - 480; base = pairz + (idx & 31); scale = 32; hk = idx >> 5; use_e = 1; }
    float4 acc = make_float4(0.f, 0.f, 0.f, 0.f);

    for (int cs = 0; cs < deg; cs += CAPA) {
        int cnt = min(CAPA, deg - cs);
        int p0 = row0 + cs;
        __syncthreads();   // protect slist/al from previous chunk's aggregate
        for (int i = t; i < cnt; i += 256) slist[i] = src_csr[p0 + i];
        __syncthreads();
        // ---- logit phase: raw logits -> al[i*12+h] ----
        for (int i = w * 2; i < cnt; i += 8) {
            int i1 = min(i + 1, cnt - 1);
            int s0 = slist[i], s1 = slist[i1];
            float em0 = 100000.0f * (mask[s0] * mdst - 1.0f);
            float em1 = 100000.0f * (mask[s1] * mdst - 1.0f);
            float kv0[3], kv1[3];
            #pragma unroll
            for (int tp = 0; tp < 3; tp++) {
                kv0[tp] = kh[(long)s0 * 192 + tp * 64 + l];
                kv1[tp] = kh[(long)s1 * 192 + tp * 64 + l];
            }
            float kp0[3] = {0.f,0.f,0.f}, kp1[3] = {0.f,0.f,0.f};
            if (c < 12) {
                #pragma unroll
                for (int tp = 0; tp < 3; tp++) {
                    int h = tp * 4 + hq;
                    kp0[tp] = kpts[(long)s0 * 144 + h * 12 + c];
                    kp1[tp] = kpts[(long)s1 * 144 + h * 12 + c];
                }
            }
            float be0[3] = {0.f,0.f,0.f}, be1[3] = {0.f,0.f,0.f};
            if (c == 0) {
                #pragma unroll
                for (int tp = 0; tp < 3; tp++) {
                    int h = tp * 4 + hq;
                    be0[tp] = b_e[(long)(p0 + i) * 12 + h];
                    be1[tp] = b_e[(long)(p0 + i1) * 12 + h];
                }
            }
            #pragma unroll
            for (int tp = 0; tp < 3; tp++) {
                int h = tp * 4 + hq;
                float qfv = S1C * qf[h * 16 + c];
                float val0 = qfv * kv0[tp];
                float val1 = qfv * kv1[tp];
                if (c < 12) {
                    float qpv = qp[h * 12 + c];
                    float hw = -0.5f * hws[h];
                    float d0 = qpv - kp0[tp];
                    float d1 = qpv - kp1[tp];
                    val0 = fmaf(hw * d0, d0, val0);
                    val1 = fmaf(hw * d1, d1, val1);
                }
                val0 += __shfl_xor(val0, 8, 16); val1 += __shfl_xor(val1, 8, 16);
                val0 += __shfl_xor(val0, 4, 16); val1 += __shfl_xor(val1, 4, 16);
                val0 += __shfl_xor(val0, 2, 16); val1 += __shfl_xor(val1, 2, 16);
                val0 += __shfl_xor(val0, 1, 16); val1 += __shfl_xor(val1, 1, 16);
                if (c == 0) {
                    al[i * 12 + h] = val0 + S2C * be0[tp] + em0;
                    if (i1 != i)
                        al[i1 * 12 + h] = val1 + S2C * be1[tp] + em1;
                }
            }
        }
        __syncthreads();
        // ---- chunk max per head, merge into running max ----
        if (l16 < 12) {
            float lm = -1e30f;
            for (int i = g; i < cnt; i += 16) lm = fmaxf(lm, al[i * 12 + l16]);
            red[g * 12 + l16] = lm;
        }
        __syncthreads();
        if (t < 12) {
            float m = mh[t];
            for (int gg = 0; gg < 16; gg++) m = fmaxf(m, red[gg * 12 + t]);
            rh[t] = expf(mh[t] - m);   // first chunk: exp(-inf)=0, acc is 0 anyway
            mh[t] = m;
        }
        __syncthreads();
        // ---- exp conversion (unnormalized p) + chunk sums ----
        if (l16 < 12) {
            float m = mh[l16];
            float ls = 0.f;
            for (int i = g; i < cnt; i += 16) {
                float p = expf(al[i * 12 + l16] - m);
                al[i * 12 + l16] = p;
                ls += p;
            }
            red[g * 12 + l16] = ls;
        }
        __syncthreads();
        if (t < 12) {
            float ss = 0.f;
            for (int gg = 0; gg < 16; gg++) ss += red[gg * 12 + t];
            lh[t] = lh[t] * rh[t] + ss;
        }
        __syncthreads();
        // ---- aggregate chunk (rescale running acc by rh[hk]) ----
        if (t < 216) {
            float r = rh[hk];
            acc.x *= r; acc.y *= r; acc.z *= r; acc.w *= r;
            int i = 0;
            for (; i + 4 <= cnt; i += 4) {
                int i0 = use_e ? (p0 + i)     : slist[i];
                int i1 = use_e ? (p0 + i + 1) : slist[i+1];
                int i2 = use_e ? (p0 + i + 2) : slist[i+2];
                int i3 = use_e ? (p0 + i + 3) : slist[i+3];
                float4 v0 = *(const float4*)(base + (long)i0 * scale);
                float4 v1 = *(const float4*)(base + (long)i1 * scale);
                float4 v2 = *(const float4*)(base + (long)i2 * scale);
                float4 v3 = *(const float4*)(base + (long)i3 * scale);
                float w0 = al[i * 12 + hk];
                float w1 = al[(i+1) * 12 + hk];
                float w2 = al[(i+2) * 12 + hk];
                float w3 = al[(i+3) * 12 + hk];
                acc.x = fmaf(w0, v0.x, acc.x); acc.y = fmaf(w0, v0.y, acc.y);
                acc.z = fmaf(w0, v0.z, acc.z); acc.w = fmaf(w0, v0.w, acc.w);
                acc.x = fmaf(w1, v1.x, acc.x); acc.y = fmaf(w1, v1.y, acc.y);
                acc.z = fmaf(w1, v1.z, acc.z); acc.w = fmaf(w1, v1.w, acc.w);
                acc.x = fmaf(w2, v2.x, acc.x); acc.y = fmaf(w2, v2.y, acc.y);
                acc.z = fmaf(w2, v2.z, acc.z); acc.w = fmaf(w2, v2.w, acc.w);
                acc.x = fmaf(w3, v3.x, acc.x); acc.y = fmaf(w3, v3.y, acc.y);
                acc.z = fmaf(w3, v3.z, acc.z); acc.w = fmaf(w3, v3.w, acc.w);
            }
            for (; i < cnt; i++) {
                int ii = use_e ? (p0 + i) : slist[i];
                float4 v = *(const float4*)(base + (long)ii * scale);
                float wv = al[i * 12 + hk];
                acc.x = fmaf(wv, v.x, acc.x); acc.y = fmaf(wv, v.y, acc.y);
                acc.z = fmaf(wv, v.z, acc.z); acc.w = fmaf(wv, v.w, acc.w);
            }
        }
    }
    // ---- epilogue: normalize -> LDS -> feature build -> feats ----
    __syncthreads();
    if (t < 216) {
        float linv = 1.f / (lh[hk] + 1e-16f);
        aggl[comp + 0] = acc.x * linv;
        aggl[comp + 1] = acc.y * linv;
        aggl[comp + 2] = acc.z * linv;
        aggl[comp + 3] = acc.w * linv;
    }
    __syncthreads();
    float* f = feats + (long)n * FEAT_D;
    if (t < 192) f[t] = aggl[t];
    if (t < 96) {
        int p = t;
        float gx = aggl[192 + p * 3 + 0] - T[0];
        float gy = aggl[192 + p * 3 + 1] - T[1];
        float gz = aggl[192 + p * 3 + 2] - T[2];
        float lx = R[0] * gx + R[3] * gy + R[6] * gz;
        float ly = R[1] * gx + R[4] * gy + R[7] * gz;
        float lz = R[2] * gx + R[5] * gy + R[8] * gz;
        f[192 + p] = lx;
        f[288 + p] = ly;
        f[384 + p] = lz;
        f[480 + p] = sqrtf(lx * lx + ly * ly + lz * lz + 1e-8f);
    }
    for (int q = t; q < 384; q += 256) f[576 + q] = aggl[480 + q];
}

// ---- output GEMM: [10000 x 960] @ wout[960 x 384] + bout ----
// OBM=32: grid 313x3=939 blocks (was 471 at BM=64 -> 1.8/CU, latency-exposed)
#define OBM 32
__global__ __launch_bounds__(256) void k_out(const float* __restrict__ feats,
    const float* __restrict__ wout, const float* __restrict__ bout,
    float* __restrict__ out) {
    __shared__ float sT[BK][OBM + 4];
    __shared__ float wt[BK][BN];
    int t = threadIdx.x;
    int bm0 = blockIdx.x * OBM;
    int bn0 = blockIdx.y * BN;
    int tcol = t & 31;
    int trow = t >> 5;
    int c0 = tcol * 4;
    int r0 = trow * 4;

    int srow = t >> 3;          // 0..31
    int skoff = (t & 7) * 4;    // 0..28
    int gsrow = min(bm0 + srow, N_RESC - 1);
    const float* srcp = feats + (long)gsrow * FEAT_D + skoff;

    float acc[4][4];
    #pragma unroll
    for (int i = 0; i < 4; i++)
        #pragma unroll
        for (int j = 0; j < 4; j++) acc[i][j] = 0.f;

    for (int k0 = 0; k0 < FEAT_D; k0 += BK) {
        float4 sa = *(const float4*)(srcp + k0);
        sT[skoff + 0][srow] = sa.x; sT[skoff + 1][srow] = sa.y;
        sT[skoff + 2][srow] = sa.z; sT[skoff + 3][srow] = sa.w;
        #pragma unroll
        for (int q = 0; q < 4; q++) {
            int kk = (t >> 5) + q * 8;
            *(float4*)&wt[kk][c0] =
                *(const float4*)(wout + (long)(k0 + kk) * OUT_D + bn0 + c0);
        }
        __syncthreads();
        #pragma unroll
        for (int k = 0; k < BK; k++) {
            float4 a0 = *(const float4*)&sT[k][r0];
            float4 b  = *(const float4*)&wt[k][c0];
            float av0 = a0.x, av1 = a0.y, av2 = a0.z, av3 = a0.w;
            acc[0][0] = fmaf(av0, b.x, acc[0][0]); acc[0][1] = fmaf(av0, b.y, acc[0][1]);
            acc[0][2] = fmaf(av0, b.z, acc[0][2]); acc[0][3] = fmaf(av0, b.w, acc[0][3]);
            acc[1][0] = fmaf(av1, b.x, acc[1][0]); acc[1][1] = fmaf(av1, b.y, acc[1][1]);
            acc[1][2] = fmaf(av1, b.z, acc[1][2]); acc[1][3] = fmaf(av1, b.w, acc[1][3]);
            acc[2][0] = fmaf(av2, b.x, acc[2][0]); acc[2][1] = fmaf(av2, b.y, acc[2][1]);
            acc[2][2] = fmaf(av2, b.z, acc[2][2]); acc[2][3] = fmaf(av2, b.w, acc[2][3]);
            acc[3][0] = fmaf(av3, b.x, acc[3][0]); acc[3][1] = fmaf(av3, b.y, acc[3][1]);
            acc[3][2] = fmaf(av3, b.z, acc[3][2]); acc[3][3] = fmaf(av3, b.w, acc[3][3]);
        }
        __syncthreads();
    }
    float bv0 = bout[bn0 + c0 + 0];
    float bv1 = bout[bn0 + c0 + 1];
    float bv2 = bout[bn0 + c0 + 2];
    float bv3 = bout[bn0 + c0 + 3];
    #pragma unroll
    for (int i = 0; i < 4; i++) {
        int n = bm0 + r0 + i;
        if (n < N_RESC) {
            *(float4*)(out + (long)n * OUT_D + bn0 + c0) =
                make_float4(acc[i][0] + bv0, acc[i][1] + bv1,
                            acc[i][2] + bv2, acc[i][3] + bv3);
        }
    }
}

extern "C" void kernel_launch(void* const* d_in, const int* in_sizes, int n_in,
                              void* d_out, int out_size, void* d_ws, size_t ws_size,
                              hipStream_t stream) {
    const float* s     = (const float*)d_in[0];
    const float* z     = (const float*)d_in[1];
    const float* rot   = (const float*)d_in[2];
    const float* trans = (const float*)d_in[3];
    const float* mask  = (const float*)d_in[4];
    const int*   ei    = (const int*)d_in[5];
    const float* wq    = (const float*)d_in[6];
    const float* bq    = (const float*)d_in[7];
    const float* wkv   = (const float*)d_in[8];
    const float* bkv   = (const float*)d_in[9];
    const float* wqp   = (const float*)d_in[10];
    const float* bqp   = (const float*)d_in[11];
    const float* wkvp  = (const float*)d_in[12];
    const float* bkvp  = (const float*)d_in[13];
    const float* wb    = (const float*)d_in[14];
    const float* bb    = (const float*)d_in[15];
    const float* wdz   = (const float*)d_in[16];
    const float* bdz   = (const float*)d_in[17];
    const float* head_w= (const float*)d_in[18];
    const float* wout  = (const float*)d_in[19];
    const float* bout  = (const float*)d_in[20];
    float* out = (float*)d_out;

    float* ws    = (float*)d_ws;
    float* qh    = ws;                         // 1,920,000
    float* kh    = qh + 1920000;               // 1,920,000
    float* vh    = kh + 1920000;               // 1,920,000
    float* qpts  = vh + 1920000;               // 1,440,000
    float* kpts  = qpts + 1440000;             // 1,440,000
    float* vpts  = kpts + 1440000;             // 2,880,000
    float* b_e   = vpts + 2880000;             // 3,840,000  (CSR order)
    float* pairz = b_e + 3840000;              // 10,240,000 (CSR order)
    float* alog  = pairz + 10240000;           // 3,840,000 (region reused by feats)
    float* agg   = alog + 3840000;             // 8,640,000 (region reused)
    // feats = alog..alog+9.6M = alog(3.84M) + agg's first 5.76M floats.
    // praw (= agg base) is consumed by k_rot BEFORE k_attn writes feats. ✓
    // wpack starts at agg+5.76M = exactly feats end; dead before k_attn. ✓
    float* feats = alog;                       // 9,600,000 floats
    float* praw  = agg;                        // alias: praw (5.76M floats)
    float* wpack = agg + 5760000;              // alias: 442,368 floats
    float* bpack = wpack + 442368;             // alias: 1,152 floats
    float* wzpack= bpack + 1152;               // alias: 6,144 floats
    float* bzpack= wzpack + 6144;              // alias: 48 floats (total < 8.64M)
    int* rowptr  = (int*)(agg + 8640000);      // 10001 (+pad)
    int* cursor  = rowptr + 10004;
    int* csr     = cursor + 10000;
    int* src_csr = csr + N_EDGEC;
    int* epos    = src_csr + N_EDGEC;

    // CSR build by dst
    k_zero<<<(N_RESC + 255) / 256, 256, 0, stream>>>(cursor);
    k_hist<<<(N_EDGEC + 255) / 256, 256, 0, stream>>>(ei, cursor);
    k_scan<<<1, 1024, 0, stream>>>(cursor, rowptr);
    k_scatter<<<(N_EDGEC + 255) / 256, 256, 0, stream>>>(ei, cursor, csr, src_csr, epos);

    // weight repack (proj + zproj), then tiled projection GEMM
    k_wpack<<<(384 * 1152 + 255) / 256, 256, 0, stream>>>(wq, bq, wkv, bkv, wqp, bqp,
                                                          wkvp, bkvp, wb, bb, wdz, bdz,
                                                          wpack, bpack, wzpack, bzpack);
    dim3 pgrid((N_RESC + BM - 1) / BM, 1152 / BN);
    k_proj<<<pgrid, 256, 0, stream>>>(s, wpack, bpack, qh, kh, vh, praw);
    k_rot<<<N_RESC, 192, 0, stream>>>(praw, rot, trans, qpts, kpts, vpts);

    // edge z-projection: tiled GEMM, contiguous z reads, CSR-scattered outputs
    k_zproj<<<N_EDGEC / ZBM, 256, 0, stream>>>(z, epos, wzpack, bzpack, b_e, pairz);

    // fused logits + softmax + aggregation + feature build
    k_attn<<<N_RESC, 256, 0, stream>>>(rowptr, src_csr, qh, kh, qpts, kpts,
                                       mask, head_w, b_e, vh, vpts, pairz,
                                       rot, trans, feats);

    // output GEMM
    dim3 ogrid((N_RESC + OBM - 1) / OBM, OUT_D / BN);
    k_out<<<ogrid, 256, 0, stream>>>(feats, wout, bout, out);
}